// Round 1
// baseline (4863.821 us; speedup 1.0000x reference)
//
#include <hip/hip_runtime.h>
#include <hip/hip_bf16.h>
#include <math.h>

#define N_NODES 100000
#define N_HE    50000
#define N_INC   600000
#define D_IN    256
#define D_H     128
#define N_CLASSES 40

__device__ __forceinline__ float sigmoidf_(float x) {
    return 1.0f / (1.0f + expf(-x));
}

// ---------------------------------------------------------------------------
// Tiled fp32 GEMM:  C(M x 128) = act( [A1 | A2](M x (K1+K2)) @ W((K1+K2) x 128) + bias )
// BM=64, BN=128 (full), BK=8. 256 threads; micro-tile 4 rows x 8 cols.
// ---------------------------------------------------------------------------
#define BM 64
#define BK 8

__global__ __launch_bounds__(256) void gemm128_kernel(
    const float* __restrict__ A1, int K1,
    const float* __restrict__ A2, int K2,
    const float* __restrict__ W,      // (K1+K2) x 128
    const float* __restrict__ bias,   // 128
    float* __restrict__ C,            // M x 128
    int M, int act)
{
    __shared__ float sX[BK][BM + 1];  // transposed: sX[k][m]
    __shared__ float sW[BK][128];

    const int tid = threadIdx.x;
    const int tx = tid & 15;   // col group: cols [tx*4..tx*4+3] and [64+tx*4..64+tx*4+3]
    const int ty = tid >> 4;   // row group: rows [ty*4..ty*4+3]
    const int row0 = blockIdx.x * BM;
    const int K = K1 + K2;

    float acc[4][8];
#pragma unroll
    for (int i = 0; i < 4; ++i)
#pragma unroll
        for (int j = 0; j < 8; ++j) acc[i][j] = 0.0f;

    for (int k0 = 0; k0 < K; k0 += BK) {
        // ---- stage X tile (64 rows x 8 cols), transposed into LDS ----
        {
            const int c = tid & 7;
            int r = tid >> 3;  // 0..31, two passes
#pragma unroll
            for (int p = 0; p < 2; ++p, r += 32) {
                const int gr = row0 + r;
                const int gk = k0 + c;
                float v = 0.0f;
                if (gr < M) {
                    if (gk < K1) v = A1[(size_t)gr * K1 + gk];
                    else         v = A2[(size_t)gr * K2 + (gk - K1)];
                }
                sX[c][r] = v;
            }
        }
        // ---- stage W tile (8 x 128) ----
#pragma unroll
        for (int p = 0; p < 4; ++p) {
            const int idx = tid + p * 256;       // 0..1023
            const int wr = idx >> 7, wc = idx & 127;
            sW[wr][wc] = W[(size_t)(k0 + wr) * 128 + wc];
        }
        __syncthreads();

#pragma unroll
        for (int kk = 0; kk < BK; ++kk) {
            float a[4];
#pragma unroll
            for (int i = 0; i < 4; ++i) a[i] = sX[kk][ty * 4 + i];
            const float4 b0 = *(const float4*)&sW[kk][tx * 4];
            const float4 b1 = *(const float4*)&sW[kk][64 + tx * 4];
#pragma unroll
            for (int i = 0; i < 4; ++i) {
                acc[i][0] += a[i] * b0.x; acc[i][1] += a[i] * b0.y;
                acc[i][2] += a[i] * b0.z; acc[i][3] += a[i] * b0.w;
                acc[i][4] += a[i] * b1.x; acc[i][5] += a[i] * b1.y;
                acc[i][6] += a[i] * b1.z; acc[i][7] += a[i] * b1.w;
            }
        }
        __syncthreads();
    }

    // ---- epilogue: bias + optional sigmoid, float4 stores ----
    const float4 bb0 = *(const float4*)(bias + tx * 4);
    const float4 bb1 = *(const float4*)(bias + 64 + tx * 4);
#pragma unroll
    for (int i = 0; i < 4; ++i) {
        const int gr = row0 + ty * 4 + i;
        if (gr >= M) continue;
        float4 o0, o1;
        o0.x = acc[i][0] + bb0.x; o0.y = acc[i][1] + bb0.y;
        o0.z = acc[i][2] + bb0.z; o0.w = acc[i][3] + bb0.w;
        o1.x = acc[i][4] + bb1.x; o1.y = acc[i][5] + bb1.y;
        o1.z = acc[i][6] + bb1.z; o1.w = acc[i][7] + bb1.w;
        if (act) {
            o0.x = sigmoidf_(o0.x); o0.y = sigmoidf_(o0.y);
            o0.z = sigmoidf_(o0.z); o0.w = sigmoidf_(o0.w);
            o1.x = sigmoidf_(o1.x); o1.y = sigmoidf_(o1.y);
            o1.z = sigmoidf_(o1.z); o1.w = sigmoidf_(o1.w);
        }
        *(float4*)(C + (size_t)gr * 128 + tx * 4) = o0;
        *(float4*)(C + (size_t)gr * 128 + 64 + tx * 4) = o1;
    }
}

// ---------------------------------------------------------------------------
// Scatter: dst[sidx[e]] += vals[e] * src[gidx[e]]  over 128 cols.
// One thread handles (incidence e, 4 consecutive cols).
// ---------------------------------------------------------------------------
__global__ __launch_bounds__(256) void scatter_kernel(
    const float* __restrict__ src, float* __restrict__ dst,
    const int* __restrict__ gidx, const int* __restrict__ sidx,
    const float* __restrict__ vals, int n)
{
    const int i = blockIdx.x * 256 + threadIdx.x;
    if (i >= n * 32) return;
    const int e = i >> 5;
    const int j = (i & 31) << 2;
    const int g = gidx[e];
    const int s = sidx[e];
    const float v = vals[e];
    const float4 t = *(const float4*)(src + (size_t)g * 128 + j);
    float* d = dst + (size_t)s * 128 + j;
    atomicAdd(d + 0, t.x * v);
    atomicAdd(d + 1, t.y * v);
    atomicAdd(d + 2, t.z * v);
    atomicAdd(d + 3, t.w * v);
}

// ---------------------------------------------------------------------------
__global__ __launch_bounds__(256) void zero_kernel(float4* __restrict__ p, int n4)
{
    const int i = blockIdx.x * 256 + threadIdx.x;
    if (i < n4) { float4 z; z.x = z.y = z.z = z.w = 0.0f; p[i] = z; }
}

// x = sigmoid(x + m), float4-vectorized
__global__ __launch_bounds__(256) void update_kernel(
    float* __restrict__ x, const float* __restrict__ m, int n4)
{
    const int i = blockIdx.x * 256 + threadIdx.x;
    if (i >= n4) return;
    float4 a = ((const float4*)x)[i];
    const float4 b = ((const float4*)m)[i];
    a.x = sigmoidf_(a.x + b.x);
    a.y = sigmoidf_(a.y + b.y);
    a.z = sigmoidf_(a.z + b.z);
    a.w = sigmoidf_(a.w + b.w);
    ((float4*)x)[i] = a;
}

// ---------------------------------------------------------------------------
// Output GEMM: out(M x 40) = X(M x 128) @ W(128 x 40) + b. One wave per row.
// ---------------------------------------------------------------------------
__global__ __launch_bounds__(256) void out_gemm_kernel(
    const float* __restrict__ X, const float* __restrict__ W,
    const float* __restrict__ b, float* __restrict__ out, int M)
{
    __shared__ float sW[128 * 40];
    __shared__ float sB[40];
    for (int i = threadIdx.x; i < 128 * 40; i += 256) sW[i] = W[i];
    if (threadIdx.x < 40) sB[threadIdx.x] = b[threadIdx.x];
    __syncthreads();

    const int wave = threadIdx.x >> 6;
    const int lane = threadIdx.x & 63;
    const int row = blockIdx.x * 4 + wave;
    if (row >= M) return;
    const int c = lane < 40 ? lane : 0;

    float acc = 0.0f;
    const float4* xr = (const float4*)(X + (size_t)row * 128);
#pragma unroll
    for (int k4 = 0; k4 < 32; ++k4) {
        const float4 xv = xr[k4];
        const int k = k4 * 4;
        acc += xv.x * sW[(k + 0) * 40 + c];
        acc += xv.y * sW[(k + 1) * 40 + c];
        acc += xv.z * sW[(k + 2) * 40 + c];
        acc += xv.w * sW[(k + 3) * 40 + c];
    }
    if (lane < 40) out[(size_t)row * 40 + lane] = acc + sB[c];
}

// ---------------------------------------------------------------------------
extern "C" void kernel_launch(void* const* d_in, const int* in_sizes, int n_in,
                              void* d_out, int out_size, void* d_ws, size_t ws_size,
                              hipStream_t stream)
{
    const float* x0_in   = (const float*)d_in[0];
    const float* x1_in   = (const float*)d_in[1];
    const int*   node_idx = (const int*)d_in[2];
    const int*   he_idx   = (const int*)d_in[3];
    const float* inc_vals = (const float*)d_in[4];
    const float* W_enc   = (const float*)d_in[5];
    const float* b_enc   = (const float*)d_in[6];
    const float* W_msg0  = (const float*)d_in[7];   // 2 x 128 x 128
    const float* b_msg0  = (const float*)d_in[8];   // 2 x 128
    const float* W_msg1  = (const float*)d_in[9];   // 2 x 256 x 128
    const float* b_msg1  = (const float*)d_in[10];  // 2 x 128
    const float* W_out   = (const float*)d_in[11];  // 128 x 40
    const float* b_out   = (const float*)d_in[12];  // 40
    float* out = (float*)d_out;

    float* ws = (float*)d_ws;
    float* x0h     = ws;                       // 100000*128 = 12.8M floats
    float* x1h     = x0h + 12800000;           // 50000*128  = 6.4M
    float* mbuf    = x1h + 6400000;            // max(100000,? )*128 = 12.8M (m0; m1 reuses)
    float* m0_he   = mbuf + 12800000;          // 50000*128  = 6.4M
    float* m1_node = m0_he + 6400000;          // 100000*128 = 12.8M
    // total 51.2M floats = 204.8 MB

    const int gemm_blocks_n = (N_NODES + BM - 1) / BM;   // 1563
    const int gemm_blocks_h = (N_HE + BM - 1) / BM;      // 782

    // Encode
    gemm128_kernel<<<gemm_blocks_n, 256, 0, stream>>>(
        x0_in, D_IN, nullptr, 0, W_enc, b_enc, x0h, N_NODES, 0);
    gemm128_kernel<<<gemm_blocks_h, 256, 0, stream>>>(
        x1_in, D_IN, nullptr, 0, W_enc, b_enc, x1h, N_HE, 0);

    for (int l = 0; l < 2; ++l) {
        // m0 = sigmoid(x0 @ W_msg0[l] + b_msg0[l])
        gemm128_kernel<<<gemm_blocks_n, 256, 0, stream>>>(
            x0h, D_H, nullptr, 0, W_msg0 + (size_t)l * D_H * D_H,
            b_msg0 + (size_t)l * D_H, mbuf, N_NODES, 1);
        // m0_he = segsum over he
        zero_kernel<<<(1600000 + 255) / 256, 256, 0, stream>>>((float4*)m0_he, 1600000);
        scatter_kernel<<<(N_INC * 32 + 255) / 256, 256, 0, stream>>>(
            mbuf, m0_he, node_idx, he_idx, inc_vals, N_INC);
        // m1 = sigmoid([x1 || m0_he] @ W_msg1[l] + b_msg1[l])
        gemm128_kernel<<<gemm_blocks_h, 256, 0, stream>>>(
            x1h, D_H, m0_he, D_H, W_msg1 + (size_t)l * 2 * D_H * D_H,
            b_msg1 + (size_t)l * D_H, mbuf, N_HE, 1);
        // m1_node = segsum over nodes
        zero_kernel<<<(3200000 + 255) / 256, 256, 0, stream>>>((float4*)m1_node, 3200000);
        scatter_kernel<<<(N_INC * 32 + 255) / 256, 256, 0, stream>>>(
            mbuf, m1_node, he_idx, node_idx, inc_vals, N_INC);
        // updates
        update_kernel<<<(3200000 + 255) / 256, 256, 0, stream>>>(x0h, m1_node, 3200000);
        update_kernel<<<(1600000 + 255) / 256, 256, 0, stream>>>(x1h, m0_he, 1600000);
    }

    // out = x0 @ W_out + b_out
    out_gemm_kernel<<<(N_NODES + 3) / 4, 256, 0, stream>>>(x0h, W_out, b_out, out, N_NODES);
}

// Round 2
// 1407.211 us; speedup vs baseline: 3.4564x; 3.4564x over previous
//
#include <hip/hip_runtime.h>
#include <hip/hip_bf16.h>
#include <math.h>

#define N_NODES 100000
#define N_HE    50000
#define N_INC   600000
#define D_IN    256
#define D_H     128
#define N_CLASSES 40

__device__ __forceinline__ float sigmoidf_(float x) {
    return 1.0f / (1.0f + expf(-x));
}

// ---------------------------------------------------------------------------
// Tiled fp32 GEMM:  C(M x 128) = act( [A1 | A2](M x (K1+K2)) @ W((K1+K2) x 128) + bias )
// BM=64, BN=128 (full), BK=8. 256 threads; micro-tile 4 rows x 8 cols.
// ---------------------------------------------------------------------------
#define BM 64
#define BK 8

__global__ __launch_bounds__(256) void gemm128_kernel(
    const float* __restrict__ A1, int K1,
    const float* __restrict__ A2, int K2,
    const float* __restrict__ W,      // (K1+K2) x 128
    const float* __restrict__ bias,   // 128
    float* __restrict__ C,            // M x 128
    int M, int act)
{
    __shared__ float sX[BK][BM + 1];  // transposed: sX[k][m]
    __shared__ float sW[BK][128];

    const int tid = threadIdx.x;
    const int tx = tid & 15;
    const int ty = tid >> 4;
    const int row0 = blockIdx.x * BM;
    const int K = K1 + K2;

    float acc[4][8];
#pragma unroll
    for (int i = 0; i < 4; ++i)
#pragma unroll
        for (int j = 0; j < 8; ++j) acc[i][j] = 0.0f;

    for (int k0 = 0; k0 < K; k0 += BK) {
        {
            const int c = tid & 7;
            int r = tid >> 3;
#pragma unroll
            for (int p = 0; p < 2; ++p, r += 32) {
                const int gr = row0 + r;
                const int gk = k0 + c;
                float v = 0.0f;
                if (gr < M) {
                    if (gk < K1) v = A1[(size_t)gr * K1 + gk];
                    else         v = A2[(size_t)gr * K2 + (gk - K1)];
                }
                sX[c][r] = v;
            }
        }
#pragma unroll
        for (int p = 0; p < 4; ++p) {
            const int idx = tid + p * 256;
            const int wr = idx >> 7, wc = idx & 127;
            sW[wr][wc] = W[(size_t)(k0 + wr) * 128 + wc];
        }
        __syncthreads();

#pragma unroll
        for (int kk = 0; kk < BK; ++kk) {
            float a[4];
#pragma unroll
            for (int i = 0; i < 4; ++i) a[i] = sX[kk][ty * 4 + i];
            const float4 b0 = *(const float4*)&sW[kk][tx * 4];
            const float4 b1 = *(const float4*)&sW[kk][64 + tx * 4];
#pragma unroll
            for (int i = 0; i < 4; ++i) {
                acc[i][0] += a[i] * b0.x; acc[i][1] += a[i] * b0.y;
                acc[i][2] += a[i] * b0.z; acc[i][3] += a[i] * b0.w;
                acc[i][4] += a[i] * b1.x; acc[i][5] += a[i] * b1.y;
                acc[i][6] += a[i] * b1.z; acc[i][7] += a[i] * b1.w;
            }
        }
        __syncthreads();
    }

    const float4 bb0 = *(const float4*)(bias + tx * 4);
    const float4 bb1 = *(const float4*)(bias + 64 + tx * 4);
#pragma unroll
    for (int i = 0; i < 4; ++i) {
        const int gr = row0 + ty * 4 + i;
        if (gr >= M) continue;
        float4 o0, o1;
        o0.x = acc[i][0] + bb0.x; o0.y = acc[i][1] + bb0.y;
        o0.z = acc[i][2] + bb0.z; o0.w = acc[i][3] + bb0.w;
        o1.x = acc[i][4] + bb1.x; o1.y = acc[i][5] + bb1.y;
        o1.z = acc[i][6] + bb1.z; o1.w = acc[i][7] + bb1.w;
        if (act) {
            o0.x = sigmoidf_(o0.x); o0.y = sigmoidf_(o0.y);
            o0.z = sigmoidf_(o0.z); o0.w = sigmoidf_(o0.w);
            o1.x = sigmoidf_(o1.x); o1.y = sigmoidf_(o1.y);
            o1.z = sigmoidf_(o1.z); o1.w = sigmoidf_(o1.w);
        }
        *(float4*)(C + (size_t)gr * 128 + tx * 4) = o0;
        *(float4*)(C + (size_t)gr * 128 + 64 + tx * 4) = o1;
    }
}

// ---------------------------------------------------------------------------
// CSR build: zero counts -> histogram -> in-place exclusive scan -> fill
// (fill shifts off[] so that off[s] = END of segment s; start = off[s-1]).
// ---------------------------------------------------------------------------
__global__ __launch_bounds__(256) void zero_int_kernel(int* __restrict__ p, int n)
{
    const int i = blockIdx.x * 256 + threadIdx.x;
    if (i < n) p[i] = 0;
}

__global__ __launch_bounds__(256) void hist_kernel(
    const int* __restrict__ he_idx, const int* __restrict__ node_idx,
    int* __restrict__ he_cnt, int* __restrict__ node_cnt, int n)
{
    const int i = blockIdx.x * 256 + threadIdx.x;
    if (i < n) {
        atomicAdd(&he_cnt[he_idx[i]], 1);
        atomicAdd(&node_cnt[node_idx[i]], 1);
    }
}

__global__ __launch_bounds__(1024) void scan_kernel(int* __restrict__ data, int n)
{
    __shared__ int sums[1024];
    const int t = threadIdx.x;
    const int chunk = (n + 1023) >> 10;
    const int s0 = t * chunk;
    const int s1 = min(s0 + chunk, n);
    int sum = 0;
    for (int i = s0; i < s1; ++i) sum += data[i];
    sums[t] = sum;
    __syncthreads();
    for (int d = 1; d < 1024; d <<= 1) {
        const int v = (t >= d) ? sums[t - d] : 0;
        __syncthreads();
        sums[t] += v;
        __syncthreads();
    }
    int running = (t == 0) ? 0 : sums[t - 1];
    for (int i = s0; i < s1; ++i) {
        const int c = data[i];
        data[i] = running;
        running += c;
    }
}

__global__ __launch_bounds__(256) void fill_kernel(
    const int* __restrict__ node_idx, const int* __restrict__ he_idx,
    const float* __restrict__ vals,
    int* __restrict__ he_off, int* __restrict__ node_off,
    int* __restrict__ he_src, float* __restrict__ he_val,
    int* __restrict__ node_src, float* __restrict__ node_val, int n)
{
    const int e = blockIdx.x * 256 + threadIdx.x;
    if (e >= n) return;
    const int hn = he_idx[e], nd = node_idx[e];
    const float v = vals[e];
    const int p0 = atomicAdd(&he_off[hn], 1);
    he_src[p0] = nd; he_val[p0] = v;
    const int p1 = atomicAdd(&node_off[nd], 1);
    node_src[p1] = hn; node_val[p1] = v;
}

// ---------------------------------------------------------------------------
// CSR pull gather: dst[row] = sum_e val[e] * src[src_idx[e]]  (128 cols)
// One wave per segment row; lane owns 2 consecutive cols (float2).
// ---------------------------------------------------------------------------
__global__ __launch_bounds__(256) void gather_kernel(
    const float* __restrict__ src, float* __restrict__ dst,
    const int* __restrict__ off, const int* __restrict__ src_idx,
    const float* __restrict__ val, int n_seg)
{
    const int wave = threadIdx.x >> 6;
    const int lane = threadIdx.x & 63;
    const int row = blockIdx.x * 4 + wave;
    if (row >= n_seg) return;
    const int start = (row == 0) ? 0 : off[row - 1];
    const int end = off[row];
    float accx = 0.0f, accy = 0.0f;
    for (int e = start; e < end; ++e) {
        const int g = src_idx[e];
        const float v = val[e];
        const float2 t = *(const float2*)(src + (size_t)g * 128 + lane * 2);
        accx += t.x * v;
        accy += t.y * v;
    }
    float2 o; o.x = accx; o.y = accy;
    *(float2*)(dst + (size_t)row * 128 + lane * 2) = o;
}

// ---------------------------------------------------------------------------
// x = sigmoid(x + m), float4-vectorized
__global__ __launch_bounds__(256) void update_kernel(
    float* __restrict__ x, const float* __restrict__ m, int n4)
{
    const int i = blockIdx.x * 256 + threadIdx.x;
    if (i >= n4) return;
    float4 a = ((const float4*)x)[i];
    const float4 b = ((const float4*)m)[i];
    a.x = sigmoidf_(a.x + b.x);
    a.y = sigmoidf_(a.y + b.y);
    a.z = sigmoidf_(a.z + b.z);
    a.w = sigmoidf_(a.w + b.w);
    ((float4*)x)[i] = a;
}

// ---------------------------------------------------------------------------
// Output GEMM: out(M x 40) = X(M x 128) @ W(128 x 40) + b. One wave per row.
// ---------------------------------------------------------------------------
__global__ __launch_bounds__(256) void out_gemm_kernel(
    const float* __restrict__ X, const float* __restrict__ W,
    const float* __restrict__ b, float* __restrict__ out, int M)
{
    __shared__ float sW[128 * 40];
    __shared__ float sB[40];
    for (int i = threadIdx.x; i < 128 * 40; i += 256) sW[i] = W[i];
    if (threadIdx.x < 40) sB[threadIdx.x] = b[threadIdx.x];
    __syncthreads();

    const int wave = threadIdx.x >> 6;
    const int lane = threadIdx.x & 63;
    const int row = blockIdx.x * 4 + wave;
    if (row >= M) return;
    const int c = lane < 40 ? lane : 0;

    float acc = 0.0f;
    const float4* xr = (const float4*)(X + (size_t)row * 128);
#pragma unroll
    for (int k4 = 0; k4 < 32; ++k4) {
        const float4 xv = xr[k4];
        const int k = k4 * 4;
        acc += xv.x * sW[(k + 0) * 40 + c];
        acc += xv.y * sW[(k + 1) * 40 + c];
        acc += xv.z * sW[(k + 2) * 40 + c];
        acc += xv.w * sW[(k + 3) * 40 + c];
    }
    if (lane < 40) out[(size_t)row * 40 + lane] = acc + sB[c];
}

// ---------------------------------------------------------------------------
extern "C" void kernel_launch(void* const* d_in, const int* in_sizes, int n_in,
                              void* d_out, int out_size, void* d_ws, size_t ws_size,
                              hipStream_t stream)
{
    const float* x0_in   = (const float*)d_in[0];
    const float* x1_in   = (const float*)d_in[1];
    const int*   node_idx = (const int*)d_in[2];
    const int*   he_idx   = (const int*)d_in[3];
    const float* inc_vals = (const float*)d_in[4];
    const float* W_enc   = (const float*)d_in[5];
    const float* b_enc   = (const float*)d_in[6];
    const float* W_msg0  = (const float*)d_in[7];   // 2 x 128 x 128
    const float* b_msg0  = (const float*)d_in[8];   // 2 x 128
    const float* W_msg1  = (const float*)d_in[9];   // 2 x 256 x 128
    const float* b_msg1  = (const float*)d_in[10];  // 2 x 128
    const float* W_out   = (const float*)d_in[11];  // 128 x 40
    const float* b_out   = (const float*)d_in[12];  // 40
    float* out = (float*)d_out;

    float* ws = (float*)d_ws;
    float* x0h     = ws;                       // 12.8M floats
    float* x1h     = x0h + 12800000;           // 6.4M
    float* mbuf    = x1h + 6400000;            // 12.8M
    float* m0_he   = mbuf + 12800000;          // 6.4M
    float* m1_node = m0_he + 6400000;          // 12.8M
    int*   he_off   = (int*)(m1_node + 12800000);  // 50k ints (+100k node)
    int*   node_off = he_off + N_HE;               // 100k
    int*   he_src   = node_off + N_NODES;          // 600k
    float* he_val   = (float*)(he_src + N_INC);    // 600k
    int*   node_src = (int*)(he_val + N_INC);      // 600k
    float* node_val = (float*)(node_src + N_INC);  // 600k
    // total ~215 MB

    const int gemm_blocks_n = (N_NODES + BM - 1) / BM;
    const int gemm_blocks_h = (N_HE + BM - 1) / BM;

    // ---- CSR build (both directions) ----
    zero_int_kernel<<<(N_HE + N_NODES + 255) / 256, 256, 0, stream>>>(he_off, N_HE + N_NODES);
    hist_kernel<<<(N_INC + 255) / 256, 256, 0, stream>>>(he_idx, node_idx, he_off, node_off, N_INC);
    scan_kernel<<<1, 1024, 0, stream>>>(he_off, N_HE);
    scan_kernel<<<1, 1024, 0, stream>>>(node_off, N_NODES);
    fill_kernel<<<(N_INC + 255) / 256, 256, 0, stream>>>(
        node_idx, he_idx, inc_vals, he_off, node_off,
        he_src, he_val, node_src, node_val, N_INC);

    // ---- Encode ----
    gemm128_kernel<<<gemm_blocks_n, 256, 0, stream>>>(
        x0_in, D_IN, nullptr, 0, W_enc, b_enc, x0h, N_NODES, 0);
    gemm128_kernel<<<gemm_blocks_h, 256, 0, stream>>>(
        x1_in, D_IN, nullptr, 0, W_enc, b_enc, x1h, N_HE, 0);

    for (int l = 0; l < 2; ++l) {
        // m0 = sigmoid(x0 @ W_msg0[l] + b_msg0[l])
        gemm128_kernel<<<gemm_blocks_n, 256, 0, stream>>>(
            x0h, D_H, nullptr, 0, W_msg0 + (size_t)l * D_H * D_H,
            b_msg0 + (size_t)l * D_H, mbuf, N_NODES, 1);
        // m0_he = pull-gather over hyperedge CSR
        gather_kernel<<<(N_HE + 3) / 4, 256, 0, stream>>>(
            mbuf, m0_he, he_off, he_src, he_val, N_HE);
        // m1 = sigmoid([x1 || m0_he] @ W_msg1[l] + b_msg1[l])
        gemm128_kernel<<<gemm_blocks_h, 256, 0, stream>>>(
            x1h, D_H, m0_he, D_H, W_msg1 + (size_t)l * 2 * D_H * D_H,
            b_msg1 + (size_t)l * D_H, mbuf, N_HE, 1);
        // m1_node = pull-gather over node CSR
        gather_kernel<<<(N_NODES + 3) / 4, 256, 0, stream>>>(
            mbuf, m1_node, node_off, node_src, node_val, N_NODES);
        // updates
        update_kernel<<<(3200000 + 255) / 256, 256, 0, stream>>>(x0h, m1_node, 3200000);
        update_kernel<<<(1600000 + 255) / 256, 256, 0, stream>>>(x1h, m0_he, 1600000);
    }

    // out = x0 @ W_out + b_out
    out_gemm_kernel<<<(N_NODES + 3) / 4, 256, 0, stream>>>(x0h, W_out, b_out, out, N_NODES);
}

// Round 3
// 848.841 us; speedup vs baseline: 5.7300x; 1.6578x over previous
//
#include <hip/hip_runtime.h>
#include <hip/hip_bf16.h>
#include <math.h>

#define N_NODES 100000
#define N_HE    50000
#define N_INC   600000
#define D_IN    256
#define D_H     128
#define N_CLASSES 40

typedef __attribute__((ext_vector_type(8))) short short8;
typedef __attribute__((ext_vector_type(4))) float f32x4;

__device__ __forceinline__ float sigmoidf_(float x) {
    return 1.0f / (1.0f + expf(-x));
}

__device__ __forceinline__ short bfbits(float f) {
    __hip_bfloat16 h = __float2bfloat16(f);
    return *reinterpret_cast<short*>(&h);
}

__device__ __forceinline__ float bf_lo(unsigned u) { return __uint_as_float(u << 16); }
__device__ __forceinline__ float bf_hi(unsigned u) { return __uint_as_float(u & 0xffff0000u); }

// ---------------------------------------------------------------------------
// MFMA GEMM: C(M x 128) = act( [A1|A2] @ W + bias ), bf16 inputs, fp32 acc.
// Block = 256 thr (4 waves in 2x2 grid), BM=128, BN=128. Wave tile 64x64.
// W pre-transposed in global as Wt[n][k] (128 x K bf16); staged to LDS in
// 128-wide K-halves with +8 pad (2-way bank aliasing only).
// A fragments load directly from global (16B/lane), no barrier in K-loop.
// ---------------------------------------------------------------------------
template<int K, int K1, bool AF32>
__global__ __launch_bounds__(256) void gemm_mfma(
    const void* __restrict__ A1v,
    const __hip_bfloat16* __restrict__ A2,   // row len K-K1 (concat case)
    const __hip_bfloat16* __restrict__ Wt,   // 128 x K bf16, transposed
    const float* __restrict__ bias,          // 128 fp32
    __hip_bfloat16* __restrict__ C,          // M x 128 bf16
    int M, int act)
{
    constexpr int KP = 136;                    // 128 + 8 pad
    __shared__ __hip_bfloat16 sW[128 * KP];    // 34816 B

    const int tid = threadIdx.x;
    const int wave = tid >> 6, lane = tid & 63;
    const int quad = lane >> 4, nn = lane & 15;
    const int wr = wave >> 1, wc = wave & 1;
    const int row_base = blockIdx.x * 128 + wr * 64;
    const int col_base = wc * 64;

    f32x4 acc[4][4] = {};

    for (int h = 0; h < K / 128; ++h) {
        // stage K-half of Wt into LDS (16B chunks)
        for (int c = tid; c < 128 * 16; c += 256) {
            const int n = c >> 4;
            const int ko = (c & 15) * 8;
            *(uint4*)&sW[n * KP + ko] = *(const uint4*)&Wt[(size_t)n * K + h * 128 + ko];
        }
        __syncthreads();

#pragma unroll
        for (int ks = 0; ks < 4; ++ks) {
            const int kl = ks * 32 + quad * 8;   // local k in LDS
            const int kq = h * 128 + kl;         // global k
            short8 a[4];
#pragma unroll
            for (int rt = 0; rt < 4; ++rt) {
                int r = row_base + rt * 16 + nn;
                if (r >= M) r = M - 1;
                if constexpr (AF32) {
                    const float* ap = (const float*)A1v + (size_t)r * K + kq;
                    const float4 p = *(const float4*)ap;
                    const float4 q = *(const float4*)(ap + 4);
                    short8 t;
                    t[0] = bfbits(p.x); t[1] = bfbits(p.y);
                    t[2] = bfbits(p.z); t[3] = bfbits(p.w);
                    t[4] = bfbits(q.x); t[5] = bfbits(q.y);
                    t[6] = bfbits(q.z); t[7] = bfbits(q.w);
                    a[rt] = t;
                } else {
                    const __hip_bfloat16* base;
                    if (K1 == K || kq < K1)
                        base = (const __hip_bfloat16*)A1v + (size_t)r * K1 + kq;
                    else
                        base = A2 + (size_t)r * (K - K1) + (kq - K1);
                    a[rt] = *(const short8*)base;
                }
            }
#pragma unroll
            for (int ct = 0; ct < 4; ++ct) {
                const short8 b = *(const short8*)&sW[(col_base + ct * 16 + nn) * KP + kl];
#pragma unroll
                for (int rt = 0; rt < 4; ++rt)
                    acc[rt][ct] = __builtin_amdgcn_mfma_f32_16x16x32_bf16(
                        a[rt], b, acc[rt][ct], 0, 0, 0);
            }
        }
        __syncthreads();
    }

    float bs[4];
#pragma unroll
    for (int ct = 0; ct < 4; ++ct) bs[ct] = bias[col_base + ct * 16 + nn];

#pragma unroll
    for (int rt = 0; rt < 4; ++rt) {
#pragma unroll
        for (int i = 0; i < 4; ++i) {
            const int r = row_base + rt * 16 + quad * 4 + i;
            if (r < M) {
#pragma unroll
                for (int ct = 0; ct < 4; ++ct) {
                    float v = acc[rt][ct][i] + bs[ct];
                    if (act) v = sigmoidf_(v);
                    C[(size_t)r * 128 + col_base + ct * 16 + nn] = __float2bfloat16(v);
                }
            }
        }
    }
}

// ---------------------------------------------------------------------------
// Weight prep: convert+transpose all GEMM weights fp32 -> bf16 Wt[n][k].
// Layout: [enc 128x256][msg0 l0 128x128][msg0 l1][msg1 l0 128x256][msg1 l1]
// ---------------------------------------------------------------------------
__global__ __launch_bounds__(256) void wprep_kernel(
    const float* __restrict__ We, const float* __restrict__ Wm0,
    const float* __restrict__ Wm1,
    __hip_bfloat16* __restrict__ Wt_enc, __hip_bfloat16* __restrict__ Wt_m0,
    __hip_bfloat16* __restrict__ Wt_m1)
{
    const int i = blockIdx.x * 256 + threadIdx.x;  // 0..131071
    const float* src; __hip_bfloat16* dst; int K, j;
    if (i < 32768)      { src = We; dst = Wt_enc; K = 256; j = i; }
    else if (i < 65536) { j = i - 32768; const int l = j >> 14;
                          src = Wm0 + l * 16384; dst = Wt_m0 + l * 16384;
                          j &= 16383; K = 128; }
    else                { j = i - 65536; const int l = j >> 15;
                          src = Wm1 + l * 32768; dst = Wt_m1 + l * 32768;
                          j &= 32767; K = 256; }
    const int n = (K == 256) ? (j >> 8) : (j >> 7);
    const int k = j & (K - 1);
    dst[(size_t)n * K + k] = __float2bfloat16(src[(size_t)k * 128 + n]);
}

// ---------------------------------------------------------------------------
// CSR build
// ---------------------------------------------------------------------------
__global__ __launch_bounds__(256) void zero_int_kernel(int* __restrict__ p, int n)
{
    const int i = blockIdx.x * 256 + threadIdx.x;
    if (i < n) p[i] = 0;
}

__global__ __launch_bounds__(256) void hist_kernel(
    const int* __restrict__ he_idx, const int* __restrict__ node_idx,
    int* __restrict__ he_cnt, int* __restrict__ node_cnt, int n)
{
    const int i = blockIdx.x * 256 + threadIdx.x;
    if (i < n) {
        atomicAdd(&he_cnt[he_idx[i]], 1);
        atomicAdd(&node_cnt[node_idx[i]], 1);
    }
}

// Parallel exclusive scan over the combined [he_cnt | node_cnt] array
// (length 150000). Node part later corrected by -N_INC (he counts sum to
// exactly N_INC).
__global__ __launch_bounds__(256) void scan1_kernel(
    int* __restrict__ data, int* __restrict__ bsums, int n)
{
    __shared__ int s[256];
    const int t = threadIdx.x;
    const int base = blockIdx.x * 1024 + t * 4;
    int4 v = make_int4(0, 0, 0, 0);
    if (base < n) v = *(const int4*)(data + base);
    s[t] = v.x + v.y + v.z + v.w;
    __syncthreads();
    for (int d = 1; d < 256; d <<= 1) {
        const int u = (t >= d) ? s[t - d] : 0;
        __syncthreads();
        s[t] += u;
        __syncthreads();
    }
    if (t == 255) bsums[blockIdx.x] = s[255];
    int e = t ? s[t - 1] : 0;
    if (base < n) {
        int4 o;
        o.x = e; e += v.x; o.y = e; e += v.y; o.z = e; e += v.z; o.w = e;
        *(int4*)(data + base) = o;
    }
}

__global__ __launch_bounds__(256) void scan2_kernel(int* __restrict__ bsums, int nb)
{
    __shared__ int s[256];
    const int t = threadIdx.x;
    const int v = (t < nb) ? bsums[t] : 0;
    s[t] = v;
    __syncthreads();
    for (int d = 1; d < 256; d <<= 1) {
        const int u = (t >= d) ? s[t - d] : 0;
        __syncthreads();
        s[t] += u;
        __syncthreads();
    }
    if (t < nb) bsums[t] = s[t] - v;  // exclusive
}

__global__ __launch_bounds__(256) void scan3_kernel(
    int* __restrict__ data, const int* __restrict__ bsums, int n)
{
    const int base = blockIdx.x * 1024 + threadIdx.x * 4;
    if (base >= n) return;
    const int adj = bsums[blockIdx.x] - ((base >= N_HE) ? N_INC : 0);
    int4 v = *(int4*)(data + base);
    v.x += adj; v.y += adj; v.z += adj; v.w += adj;
    *(int4*)(data + base) = v;
}

__global__ __launch_bounds__(256) void fill_kernel(
    const int* __restrict__ node_idx, const int* __restrict__ he_idx,
    const float* __restrict__ vals,
    int* __restrict__ he_off, int* __restrict__ node_off,
    int* __restrict__ he_src, float* __restrict__ he_val,
    int* __restrict__ node_src, float* __restrict__ node_val, int n)
{
    const int e = blockIdx.x * 256 + threadIdx.x;
    if (e >= n) return;
    const int hn = he_idx[e], nd = node_idx[e];
    const float v = vals[e];
    const int p0 = atomicAdd(&he_off[hn], 1);
    he_src[p0] = nd; he_val[p0] = v;
    const int p1 = atomicAdd(&node_off[nd], 1);
    node_src[p1] = hn; node_val[p1] = v;
}

// ---------------------------------------------------------------------------
// CSR pull gather (bf16): dst[row] = sum_e val[e] * src[src_idx[e]] (128 cols)
// One wave per row; lane owns 2 cols (4B load), fp32 accumulate, bf16 store.
// ---------------------------------------------------------------------------
__global__ __launch_bounds__(256) void gather_kernel(
    const __hip_bfloat16* __restrict__ src, __hip_bfloat16* __restrict__ dst,
    const int* __restrict__ off, const int* __restrict__ src_idx,
    const float* __restrict__ val, int n_seg)
{
    const int wave = threadIdx.x >> 6;
    const int lane = threadIdx.x & 63;
    const int row = blockIdx.x * 4 + wave;
    if (row >= n_seg) return;
    const int start = row ? off[row - 1] : 0;
    const int end = off[row];
    float ax = 0.0f, ay = 0.0f;
    const unsigned short* s16 = (const unsigned short*)src;
    for (int e = start; e < end; ++e) {
        const int g = src_idx[e];
        const float v = val[e];
        const unsigned u = *(const unsigned*)(s16 + (size_t)g * 128 + lane * 2);
        ax += bf_lo(u) * v;
        ay += bf_hi(u) * v;
    }
    const unsigned lo = (unsigned short)bfbits(ax);
    const unsigned hi = (unsigned short)bfbits(ay);
    *(unsigned*)((unsigned short*)dst + (size_t)row * 128 + lane * 2) = lo | (hi << 16);
}

// ---------------------------------------------------------------------------
// x = sigmoid(x + m), bf16, 8 elems/thread
// ---------------------------------------------------------------------------
__global__ __launch_bounds__(256) void update_kernel(
    __hip_bfloat16* __restrict__ x, const __hip_bfloat16* __restrict__ m, int n8)
{
    const int i = blockIdx.x * 256 + threadIdx.x;
    if (i >= n8) return;
    uint4 xa = ((const uint4*)x)[i];
    const uint4 ma = ((const uint4*)m)[i];
    unsigned* px = (unsigned*)&xa;
    const unsigned* pm = (const unsigned*)&ma;
#pragma unroll
    for (int w = 0; w < 4; ++w) {
        const float s0 = sigmoidf_(bf_lo(px[w]) + bf_lo(pm[w]));
        const float s1 = sigmoidf_(bf_hi(px[w]) + bf_hi(pm[w]));
        px[w] = (unsigned)(unsigned short)bfbits(s0)
              | ((unsigned)(unsigned short)bfbits(s1) << 16);
    }
    ((uint4*)x)[i] = xa;
}

// ---------------------------------------------------------------------------
// Output GEMM: out(M x 40) = X(M x 128 bf16) @ W(128 x 40 fp32) + b.
// One wave per row (row broadcast via L1), W in LDS.
// ---------------------------------------------------------------------------
__global__ __launch_bounds__(256) void out_gemm_kernel(
    const __hip_bfloat16* __restrict__ X, const float* __restrict__ W,
    const float* __restrict__ b, float* __restrict__ out, int M)
{
    __shared__ float sW[128 * 40];
    __shared__ float sB[40];
    for (int i = threadIdx.x; i < 128 * 40; i += 256) sW[i] = W[i];
    if (threadIdx.x < 40) sB[threadIdx.x] = b[threadIdx.x];
    __syncthreads();

    const int wave = threadIdx.x >> 6;
    const int lane = threadIdx.x & 63;
    const int row = blockIdx.x * 4 + wave;
    if (row >= M) return;
    const int c = lane < 40 ? lane : 0;

    float acc = 0.0f;
    const uint4* xr = (const uint4*)(X + (size_t)row * 128);  // 16 x uint4
#pragma unroll
    for (int i = 0; i < 16; ++i) {
        const uint4 q = xr[i];
        const unsigned* pq = (const unsigned*)&q;
#pragma unroll
        for (int w = 0; w < 4; ++w) {
            const int k = i * 8 + w * 2;
            acc += bf_lo(pq[w]) * sW[k * 40 + c];
            acc += bf_hi(pq[w]) * sW[(k + 1) * 40 + c];
        }
    }
    if (lane < 40) out[(size_t)row * 40 + lane] = acc + sB[c];
}

// ---------------------------------------------------------------------------
extern "C" void kernel_launch(void* const* d_in, const int* in_sizes, int n_in,
                              void* d_out, int out_size, void* d_ws, size_t ws_size,
                              hipStream_t stream)
{
    const float* x0_in   = (const float*)d_in[0];
    const float* x1_in   = (const float*)d_in[1];
    const int*   node_idx = (const int*)d_in[2];
    const int*   he_idx   = (const int*)d_in[3];
    const float* inc_vals = (const float*)d_in[4];
    const float* W_enc   = (const float*)d_in[5];
    const float* b_enc   = (const float*)d_in[6];
    const float* W_msg0  = (const float*)d_in[7];   // 2 x 128 x 128
    const float* b_msg0  = (const float*)d_in[8];   // 2 x 128
    const float* W_msg1  = (const float*)d_in[9];   // 2 x 256 x 128
    const float* b_msg1  = (const float*)d_in[10];  // 2 x 128
    const float* W_out   = (const float*)d_in[11];  // 128 x 40
    const float* b_out   = (const float*)d_in[12];  // 40
    float* out = (float*)d_out;

    // workspace layout (bf16 elems first, 16B-aligned offsets)
    __hip_bfloat16* x0h     = (__hip_bfloat16*)d_ws;        // 12,800,000
    __hip_bfloat16* x1h     = x0h + 12800000;               //  6,400,000
    __hip_bfloat16* mbuf    = x1h + 6400000;                // 12,800,000
    __hip_bfloat16* m0_he   = mbuf + 12800000;              //  6,400,000
    __hip_bfloat16* m1_node = m0_he + 6400000;              // 12,800,000
    __hip_bfloat16* Wt_enc  = m1_node + 12800000;           // 32768
    __hip_bfloat16* Wt_m0   = Wt_enc + 32768;               // 32768
    __hip_bfloat16* Wt_m1   = Wt_m0 + 32768;                // 65536
    int*   he_off   = (int*)(Wt_m1 + 65536);
    int*   node_off = he_off + N_HE;
    int*   bsums    = node_off + N_NODES;                   // 256
    int*   he_src   = bsums + 256;
    int*   node_src = he_src + N_INC;
    float* he_val   = (float*)(node_src + N_INC);
    float* node_val = he_val + N_INC;

    // ---- CSR build ----
    zero_int_kernel<<<(N_HE + N_NODES + 255) / 256, 256, 0, stream>>>(
        he_off, N_HE + N_NODES);
    hist_kernel<<<(N_INC + 255) / 256, 256, 0, stream>>>(
        he_idx, node_idx, he_off, node_off, N_INC);
    const int scan_n = N_HE + N_NODES;                       // 150000
    const int scan_blocks = (scan_n + 1023) / 1024;          // 147
    scan1_kernel<<<scan_blocks, 256, 0, stream>>>(he_off, bsums, scan_n);
    scan2_kernel<<<1, 256, 0, stream>>>(bsums, scan_blocks);
    scan3_kernel<<<scan_blocks, 256, 0, stream>>>(he_off, bsums, scan_n);
    fill_kernel<<<(N_INC + 255) / 256, 256, 0, stream>>>(
        node_idx, he_idx, inc_vals, he_off, node_off,
        he_src, he_val, node_src, node_val, N_INC);

    // ---- weight prep ----
    wprep_kernel<<<512, 256, 0, stream>>>(W_enc, W_msg0, W_msg1,
                                          Wt_enc, Wt_m0, Wt_m1);

    // ---- encode (fp32 A, convert in-register) ----
    gemm_mfma<256, 256, true><<<(N_NODES + 127) / 128, 256, 0, stream>>>(
        x0_in, nullptr, Wt_enc, b_enc, x0h, N_NODES, 0);
    gemm_mfma<256, 256, true><<<(N_HE + 127) / 128, 256, 0, stream>>>(
        x1_in, nullptr, Wt_enc, b_enc, x1h, N_HE, 0);

    for (int l = 0; l < 2; ++l) {
        gemm_mfma<128, 128, false><<<(N_NODES + 127) / 128, 256, 0, stream>>>(
            x0h, nullptr, Wt_m0 + (size_t)l * 16384,
            b_msg0 + (size_t)l * 128, mbuf, N_NODES, 1);
        gather_kernel<<<(N_HE + 3) / 4, 256, 0, stream>>>(
            mbuf, m0_he, he_off, he_src, he_val, N_HE);
        gemm_mfma<256, 128, false><<<(N_HE + 127) / 128, 256, 0, stream>>>(
            x1h, m0_he, Wt_m1 + (size_t)l * 32768,
            b_msg1 + (size_t)l * 128, mbuf, N_HE, 1);
        gather_kernel<<<(N_NODES + 3) / 4, 256, 0, stream>>>(
            mbuf, m1_node, node_off, node_src, node_val, N_NODES);
        update_kernel<<<(1600000 + 255) / 256, 256, 0, stream>>>(
            x0h, m1_node, 1600000);
        update_kernel<<<(800000 + 255) / 256, 256, 0, stream>>>(
            x1h, m0_he, 800000);
    }

    out_gemm_kernel<<<(N_NODES + 3) / 4, 256, 0, stream>>>(
        x0h, W_out, b_out, out, N_NODES);
}

// Round 4
// 792.993 us; speedup vs baseline: 6.1335x; 1.0704x over previous
//
#include <hip/hip_runtime.h>
#include <hip/hip_bf16.h>
#include <math.h>

#define N_NODES 100000
#define N_HE    50000
#define N_INC   600000
#define D_IN    256
#define D_H     128
#define N_CLASSES 40

typedef __attribute__((ext_vector_type(8))) short short8;
typedef __attribute__((ext_vector_type(4))) float f32x4;

__device__ __forceinline__ float sigmoidf_(float x) {
    return 1.0f / (1.0f + expf(-x));
}

__device__ __forceinline__ short bfbits(float f) {
    __hip_bfloat16 h = __float2bfloat16(f);
    return *reinterpret_cast<short*>(&h);
}

__device__ __forceinline__ float bf_lo(unsigned u) { return __uint_as_float(u << 16); }
__device__ __forceinline__ float bf_hi(unsigned u) { return __uint_as_float(u & 0xffff0000u); }
__device__ __forceinline__ unsigned bfpack(float a, float b) {
    return (unsigned)(unsigned short)bfbits(a) | ((unsigned)(unsigned short)bfbits(b) << 16);
}

// ---------------------------------------------------------------------------
// MFMA GEMM: C(M x 128) = act( [A1|A2] @ W + bias ), bf16 inputs, fp32 acc.
// Block = 256 thr (4 waves 2x2), BM=128, BN=128, wave tile 64x64.
// Wt[n][k] staged to LDS (KP=136 pad, 2-way aliasing only).
// A fragments straight from global (16B/lane), no barrier in K-loop.
// ---------------------------------------------------------------------------
template<int K, int K1, bool AF32>
__global__ __launch_bounds__(256) void gemm_mfma(
    const void* __restrict__ A1v,
    const __hip_bfloat16* __restrict__ A2,
    const __hip_bfloat16* __restrict__ Wt,   // 128 x K bf16, transposed
    const float* __restrict__ bias,
    __hip_bfloat16* __restrict__ C,          // M x 128 bf16
    int M, int act)
{
    constexpr int KP = 136;
    __shared__ __hip_bfloat16 sW[128 * KP];

    const int tid = threadIdx.x;
    const int wave = tid >> 6, lane = tid & 63;
    const int quad = lane >> 4, nn = lane & 15;
    const int wr = wave >> 1, wc = wave & 1;
    const int row_base = blockIdx.x * 128 + wr * 64;
    const int col_base = wc * 64;

    f32x4 acc[4][4] = {};

    for (int h = 0; h < K / 128; ++h) {
        for (int c = tid; c < 128 * 16; c += 256) {
            const int n = c >> 4;
            const int ko = (c & 15) * 8;
            *(uint4*)&sW[n * KP + ko] = *(const uint4*)&Wt[(size_t)n * K + h * 128 + ko];
        }
        __syncthreads();

#pragma unroll
        for (int ks = 0; ks < 4; ++ks) {
            const int kl = ks * 32 + quad * 8;
            const int kq = h * 128 + kl;
            short8 a[4];
#pragma unroll
            for (int rt = 0; rt < 4; ++rt) {
                int r = row_base + rt * 16 + nn;
                if (r >= M) r = M - 1;
                if constexpr (AF32) {
                    const float* ap = (const float*)A1v + (size_t)r * K + kq;
                    const float4 p = *(const float4*)ap;
                    const float4 q = *(const float4*)(ap + 4);
                    short8 t;
                    t[0] = bfbits(p.x); t[1] = bfbits(p.y);
                    t[2] = bfbits(p.z); t[3] = bfbits(p.w);
                    t[4] = bfbits(q.x); t[5] = bfbits(q.y);
                    t[6] = bfbits(q.z); t[7] = bfbits(q.w);
                    a[rt] = t;
                } else {
                    const __hip_bfloat16* base;
                    if (K1 == K || kq < K1)
                        base = (const __hip_bfloat16*)A1v + (size_t)r * K1 + kq;
                    else
                        base = A2 + (size_t)r * (K - K1) + (kq - K1);
                    a[rt] = *(const short8*)base;
                }
            }
#pragma unroll
            for (int ct = 0; ct < 4; ++ct) {
                const short8 b = *(const short8*)&sW[(col_base + ct * 16 + nn) * KP + kl];
#pragma unroll
                for (int rt = 0; rt < 4; ++rt)
                    acc[rt][ct] = __builtin_amdgcn_mfma_f32_16x16x32_bf16(
                        a[rt], b, acc[rt][ct], 0, 0, 0);
            }
        }
        __syncthreads();
    }

    float bs[4];
#pragma unroll
    for (int ct = 0; ct < 4; ++ct) bs[ct] = bias[col_base + ct * 16 + nn];

#pragma unroll
    for (int rt = 0; rt < 4; ++rt) {
#pragma unroll
        for (int i = 0; i < 4; ++i) {
            const int r = row_base + rt * 16 + quad * 4 + i;
            if (r < M) {
#pragma unroll
                for (int ct = 0; ct < 4; ++ct) {
                    float v = acc[rt][ct][i] + bs[ct];
                    if (act) v = sigmoidf_(v);
                    C[(size_t)r * 128 + col_base + ct * 16 + nn] = __float2bfloat16(v);
                }
            }
        }
    }
}

// ---------------------------------------------------------------------------
// MFMA output GEMM: out(M x 40) = X(M x 128 bf16) @ W + b, fp32 out.
// N padded to 48 (3 col tiles). 4 waves/block, 16 rows each, 64 rows/block.
// ---------------------------------------------------------------------------
__global__ __launch_bounds__(256) void out_gemm_mfma(
    const __hip_bfloat16* __restrict__ X,
    const __hip_bfloat16* __restrict__ Wt,   // 48 x 128 bf16 (n-major, padded)
    const float* __restrict__ b, float* __restrict__ out, int M)
{
    constexpr int KP = 136;
    __shared__ __hip_bfloat16 sW[48 * KP];
    __shared__ float sB[48];

    const int tid = threadIdx.x;
    for (int c = tid; c < 48 * 16; c += 256) {
        const int n = c >> 4, ko = (c & 15) * 8;
        *(uint4*)&sW[n * KP + ko] = *(const uint4*)&Wt[n * 128 + ko];
    }
    if (tid < 48) sB[tid] = (tid < 40) ? b[tid] : 0.0f;
    __syncthreads();

    const int wave = tid >> 6, lane = tid & 63;
    const int quad = lane >> 4, nn = lane & 15;
    const int row0 = blockIdx.x * 64 + wave * 16;

    f32x4 acc[3] = {};
#pragma unroll
    for (int ks = 0; ks < 4; ++ks) {
        int r = row0 + nn;
        if (r >= M) r = M - 1;
        const short8 a = *(const short8*)(X + (size_t)r * 128 + ks * 32 + quad * 8);
#pragma unroll
        for (int ct = 0; ct < 3; ++ct) {
            const short8 bf = *(const short8*)&sW[(ct * 16 + nn) * KP + ks * 32 + quad * 8];
            acc[ct] = __builtin_amdgcn_mfma_f32_16x16x32_bf16(a, bf, acc[ct], 0, 0, 0);
        }
    }
#pragma unroll
    for (int ct = 0; ct < 3; ++ct) {
        const int c = ct * 16 + nn;
#pragma unroll
        for (int i = 0; i < 4; ++i) {
            const int r = row0 + quad * 4 + i;
            if (r < M && c < 40) out[(size_t)r * 40 + c] = acc[ct][i] + sB[c];
        }
    }
}

// ---------------------------------------------------------------------------
// Weight prep: fp32 -> bf16 transposed Wt[n][k] for enc/m0/m1/out.
// ---------------------------------------------------------------------------
__global__ __launch_bounds__(256) void wprep_kernel(
    const float* __restrict__ We, const float* __restrict__ Wm0,
    const float* __restrict__ Wm1, const float* __restrict__ Wout,
    __hip_bfloat16* __restrict__ Wt_enc, __hip_bfloat16* __restrict__ Wt_m0,
    __hip_bfloat16* __restrict__ Wt_m1, __hip_bfloat16* __restrict__ Wt_out)
{
    const int i = blockIdx.x * 256 + threadIdx.x;  // 0..137215
    if (i < 32768) {
        const int n = i >> 8, k = i & 255;
        Wt_enc[n * 256 + k] = __float2bfloat16(We[k * 128 + n]);
    } else if (i < 65536) {
        int j = i - 32768; const int l = j >> 14; j &= 16383;
        const int n = j >> 7, k = j & 127;
        Wt_m0[l * 16384 + n * 128 + k] = __float2bfloat16(Wm0[l * 16384 + k * 128 + n]);
    } else if (i < 131072) {
        int j = i - 65536; const int l = j >> 15; j &= 32767;
        const int n = j >> 8, k = j & 255;
        Wt_m1[l * 32768 + n * 256 + k] = __float2bfloat16(Wm1[l * 32768 + k * 128 + n]);
    } else {
        const int j = i - 131072;
        const int n = j >> 7, k = j & 127;
        Wt_out[n * 128 + k] = (n < 40) ? __float2bfloat16(Wout[k * 40 + n])
                                       : __float2bfloat16(0.0f);
    }
}

// ---------------------------------------------------------------------------
// CSR build
// ---------------------------------------------------------------------------
__global__ __launch_bounds__(256) void zero_int_kernel(int* __restrict__ p, int n)
{
    const int i = blockIdx.x * 256 + threadIdx.x;
    if (i < n) p[i] = 0;
}

__global__ __launch_bounds__(256) void hist_kernel(
    const int* __restrict__ he_idx, const int* __restrict__ node_idx,
    int* __restrict__ he_cnt, int* __restrict__ node_cnt, int n)
{
    const int i = blockIdx.x * 256 + threadIdx.x;
    if (i < n) {
        atomicAdd(&he_cnt[he_idx[i]], 1);
        atomicAdd(&node_cnt[node_idx[i]], 1);
    }
}

__global__ __launch_bounds__(256) void scan1_kernel(
    int* __restrict__ data, int* __restrict__ bsums, int n)
{
    __shared__ int s[256];
    const int t = threadIdx.x;
    const int base = blockIdx.x * 1024 + t * 4;
    int4 v = make_int4(0, 0, 0, 0);
    if (base < n) v = *(const int4*)(data + base);
    s[t] = v.x + v.y + v.z + v.w;
    __syncthreads();
    for (int d = 1; d < 256; d <<= 1) {
        const int u = (t >= d) ? s[t - d] : 0;
        __syncthreads();
        s[t] += u;
        __syncthreads();
    }
    if (t == 255) bsums[blockIdx.x] = s[255];
    int e = t ? s[t - 1] : 0;
    if (base < n) {
        int4 o;
        o.x = e; e += v.x; o.y = e; e += v.y; o.z = e; e += v.z; o.w = e;
        *(int4*)(data + base) = o;
    }
}

__global__ __launch_bounds__(256) void scan2_kernel(int* __restrict__ bsums, int nb)
{
    __shared__ int s[256];
    const int t = threadIdx.x;
    const int v = (t < nb) ? bsums[t] : 0;
    s[t] = v;
    __syncthreads();
    for (int d = 1; d < 256; d <<= 1) {
        const int u = (t >= d) ? s[t - d] : 0;
        __syncthreads();
        s[t] += u;
        __syncthreads();
    }
    if (t < nb) bsums[t] = s[t] - v;
}

__global__ __launch_bounds__(256) void scan3_kernel(
    int* __restrict__ data, const int* __restrict__ bsums, int n)
{
    const int base = blockIdx.x * 1024 + threadIdx.x * 4;
    if (base >= n) return;
    const int adj = bsums[blockIdx.x] - ((base >= N_HE) ? N_INC : 0);
    int4 v = *(int4*)(data + base);
    v.x += adj; v.y += adj; v.z += adj; v.w += adj;
    *(int4*)(data + base) = v;
}

// fill packed edges: edge = {src_row, val_bits}
__global__ __launch_bounds__(256) void fill_kernel(
    const int* __restrict__ node_idx, const int* __restrict__ he_idx,
    const float* __restrict__ vals,
    int* __restrict__ he_off, int* __restrict__ node_off,
    int2* __restrict__ he_edge, int2* __restrict__ node_edge, int n)
{
    const int e = blockIdx.x * 256 + threadIdx.x;
    if (e >= n) return;
    const int hn = he_idx[e], nd = node_idx[e];
    const int vb = __float_as_int(vals[e]);
    const int p0 = atomicAdd(&he_off[hn], 1);
    he_edge[p0] = make_int2(nd, vb);
    const int p1 = atomicAdd(&node_off[nd], 1);
    node_edge[p1] = make_int2(hn, vb);
}

// ---------------------------------------------------------------------------
// Fused he-gather: agg = sum val*m0[src]; writes m0_he (bf16) AND
// x1_next = sigmoid(x1_cur + agg). One wave per he row, lane owns 2 cols.
// ---------------------------------------------------------------------------
__global__ __launch_bounds__(256) void gather_he_kernel(
    const __hip_bfloat16* __restrict__ msrc,
    const __hip_bfloat16* __restrict__ x1cur,
    __hip_bfloat16* __restrict__ m0_he,
    __hip_bfloat16* __restrict__ x1next,
    const int* __restrict__ off, const int2* __restrict__ edges, int n_seg)
{
    const int wave = threadIdx.x >> 6;
    const int lane = threadIdx.x & 63;
    const int row = blockIdx.x * 4 + wave;
    if (row >= n_seg) return;
    const int start = row ? off[row - 1] : 0;
    const int end = off[row];
    float ax = 0.0f, ay = 0.0f;
    const unsigned short* s16 = (const unsigned short*)msrc;
    for (int e = start; e < end; ++e) {
        const int2 ed = edges[e];
        const float v = __int_as_float(ed.y);
        const unsigned u = *(const unsigned*)(s16 + (size_t)ed.x * 128 + lane * 2);
        ax += bf_lo(u) * v;
        ay += bf_hi(u) * v;
    }
    const size_t o = (size_t)row * 128 + lane * 2;
    *(unsigned*)((unsigned short*)m0_he + o) = bfpack(ax, ay);
    const unsigned xu = *(const unsigned*)((const unsigned short*)x1cur + o);
    *(unsigned*)((unsigned short*)x1next + o) =
        bfpack(sigmoidf_(bf_lo(xu) + ax), sigmoidf_(bf_hi(xu) + ay));
}

// ---------------------------------------------------------------------------
// Fused node-gather: agg over m1; x0 = sigmoid(x0 + agg) in place.
// ---------------------------------------------------------------------------
__global__ __launch_bounds__(256) void gather_node_kernel(
    const __hip_bfloat16* __restrict__ msrc,
    __hip_bfloat16* __restrict__ x0,
    const int* __restrict__ off, const int2* __restrict__ edges, int n_seg)
{
    const int wave = threadIdx.x >> 6;
    const int lane = threadIdx.x & 63;
    const int row = blockIdx.x * 4 + wave;
    if (row >= n_seg) return;
    const int start = row ? off[row - 1] : 0;
    const int end = off[row];
    float ax = 0.0f, ay = 0.0f;
    const unsigned short* s16 = (const unsigned short*)msrc;
    for (int e = start; e < end; ++e) {
        const int2 ed = edges[e];
        const float v = __int_as_float(ed.y);
        const unsigned u = *(const unsigned*)(s16 + (size_t)ed.x * 128 + lane * 2);
        ax += bf_lo(u) * v;
        ay += bf_hi(u) * v;
    }
    const size_t o = (size_t)row * 128 + lane * 2;
    unsigned* px = (unsigned*)((unsigned short*)x0 + o);
    const unsigned xu = *px;
    *px = bfpack(sigmoidf_(bf_lo(xu) + ax), sigmoidf_(bf_hi(xu) + ay));
}

// ---------------------------------------------------------------------------
extern "C" void kernel_launch(void* const* d_in, const int* in_sizes, int n_in,
                              void* d_out, int out_size, void* d_ws, size_t ws_size,
                              hipStream_t stream)
{
    const float* x0_in   = (const float*)d_in[0];
    const float* x1_in   = (const float*)d_in[1];
    const int*   node_idx = (const int*)d_in[2];
    const int*   he_idx   = (const int*)d_in[3];
    const float* inc_vals = (const float*)d_in[4];
    const float* W_enc   = (const float*)d_in[5];
    const float* b_enc   = (const float*)d_in[6];
    const float* W_msg0  = (const float*)d_in[7];
    const float* b_msg0  = (const float*)d_in[8];
    const float* W_msg1  = (const float*)d_in[9];
    const float* b_msg1  = (const float*)d_in[10];
    const float* W_out   = (const float*)d_in[11];
    const float* b_out   = (const float*)d_in[12];
    float* out = (float*)d_out;

    __hip_bfloat16* x0h    = (__hip_bfloat16*)d_ws;         // 12,800,000
    __hip_bfloat16* x1a    = x0h + 12800000;                //  6,400,000
    __hip_bfloat16* x1b    = x1a + 6400000;                 //  6,400,000
    __hip_bfloat16* mbuf   = x1b + 6400000;                 // 12,800,000
    __hip_bfloat16* m0_he  = mbuf + 12800000;               //  6,400,000
    __hip_bfloat16* Wt_enc = m0_he + 6400000;               // 32768
    __hip_bfloat16* Wt_m0  = Wt_enc + 32768;                // 32768
    __hip_bfloat16* Wt_m1  = Wt_m0 + 32768;                 // 65536
    __hip_bfloat16* Wt_out = Wt_m1 + 65536;                 // 6144
    int*  he_off    = (int*)(Wt_out + 6144);
    int*  node_off  = he_off + N_HE;
    int*  bsums     = node_off + N_NODES;                   // 256
    int2* he_edge   = (int2*)(bsums + 256);
    int2* node_edge = he_edge + N_INC;

    // ---- CSR build ----
    zero_int_kernel<<<(N_HE + N_NODES + 255) / 256, 256, 0, stream>>>(
        he_off, N_HE + N_NODES);
    hist_kernel<<<(N_INC + 255) / 256, 256, 0, stream>>>(
        he_idx, node_idx, he_off, node_off, N_INC);
    const int scan_n = N_HE + N_NODES;
    const int scan_blocks = (scan_n + 1023) / 1024;          // 147
    scan1_kernel<<<scan_blocks, 256, 0, stream>>>(he_off, bsums, scan_n);
    scan2_kernel<<<1, 256, 0, stream>>>(bsums, scan_blocks);
    scan3_kernel<<<scan_blocks, 256, 0, stream>>>(he_off, bsums, scan_n);
    fill_kernel<<<(N_INC + 255) / 256, 256, 0, stream>>>(
        node_idx, he_idx, inc_vals, he_off, node_off,
        he_edge, node_edge, N_INC);

    // ---- weight prep (137216 elems / 256 = 536 blocks) ----
    wprep_kernel<<<536, 256, 0, stream>>>(W_enc, W_msg0, W_msg1, W_out,
                                          Wt_enc, Wt_m0, Wt_m1, Wt_out);

    // ---- encode ----
    gemm_mfma<256, 256, true><<<(N_NODES + 127) / 128, 256, 0, stream>>>(
        x0_in, nullptr, Wt_enc, b_enc, x0h, N_NODES, 0);
    gemm_mfma<256, 256, true><<<(N_HE + 127) / 128, 256, 0, stream>>>(
        x1_in, nullptr, Wt_enc, b_enc, x1a, N_HE, 0);

    __hip_bfloat16* x1cur = x1a;
    __hip_bfloat16* x1nxt = x1b;
    for (int l = 0; l < 2; ++l) {
        // m0 = sigmoid(x0 @ W_msg0[l] + b)
        gemm_mfma<128, 128, false><<<(N_NODES + 127) / 128, 256, 0, stream>>>(
            x0h, nullptr, Wt_m0 + (size_t)l * 16384,
            b_msg0 + (size_t)l * 128, mbuf, N_NODES, 1);
        // m0_he agg + x1 update (to x1nxt; m1 GEMM still reads x1cur)
        gather_he_kernel<<<(N_HE + 3) / 4, 256, 0, stream>>>(
            mbuf, x1cur, m0_he, x1nxt, he_off, he_edge, N_HE);
        // m1 = sigmoid([x1cur || m0_he] @ W_msg1[l] + b)
        gemm_mfma<256, 128, false><<<(N_HE + 127) / 128, 256, 0, stream>>>(
            x1cur, m0_he, Wt_m1 + (size_t)l * 32768,
            b_msg1 + (size_t)l * 128, mbuf, N_HE, 1);
        // node agg + x0 update in place
        gather_node_kernel<<<(N_NODES + 3) / 4, 256, 0, stream>>>(
            mbuf, x0h, node_off, node_edge, N_NODES);
        // swap x1 buffers
        __hip_bfloat16* t = x1cur; x1cur = x1nxt; x1nxt = t;
    }

    out_gemm_mfma<<<(N_NODES + 63) / 64, 256, 0, stream>>>(
        x0h, Wt_out, b_out, out, N_NODES);
}

// Round 5
// 665.946 us; speedup vs baseline: 7.3036x; 1.1908x over previous
//
#include <hip/hip_runtime.h>
#include <hip/hip_bf16.h>
#include <math.h>

#define N_NODES 100000
#define N_HE    50000
#define N_INC   600000
#define D_IN    256
#define D_H     128
#define N_CLASSES 40

typedef __attribute__((ext_vector_type(8))) short short8;
typedef __attribute__((ext_vector_type(4))) float f32x4;

__device__ __forceinline__ float sigmoidf_(float x) {
    return 1.0f / (1.0f + expf(-x));
}

__device__ __forceinline__ short bfbits(float f) {
    __hip_bfloat16 h = __float2bfloat16(f);
    return *reinterpret_cast<short*>(&h);
}

__device__ __forceinline__ float bf_lo(unsigned u) { return __uint_as_float(u << 16); }
__device__ __forceinline__ float bf_hi(unsigned u) { return __uint_as_float(u & 0xffff0000u); }
__device__ __forceinline__ unsigned bfpack(float a, float b) {
    return (unsigned)(unsigned short)bfbits(a) | ((unsigned)(unsigned short)bfbits(b) << 16);
}

// ---------------------------------------------------------------------------
// MFMA GEMM: C(M x 128) = act( [A1|A2] @ W + bias ), bf16 inputs, fp32 acc.
// Block = 256 thr (4 waves 2x2), BM=128, BN=128, wave tile 64x64.
// ---------------------------------------------------------------------------
template<int K, int K1, bool AF32>
__global__ __launch_bounds__(256) void gemm_mfma(
    const void* __restrict__ A1v,
    const __hip_bfloat16* __restrict__ A2,
    const __hip_bfloat16* __restrict__ Wt,   // 128 x K bf16, transposed
    const float* __restrict__ bias,
    __hip_bfloat16* __restrict__ C,          // M x 128 bf16
    int M, int act)
{
    constexpr int KP = 136;
    __shared__ __hip_bfloat16 sW[128 * KP];

    const int tid = threadIdx.x;
    const int wave = tid >> 6, lane = tid & 63;
    const int quad = lane >> 4, nn = lane & 15;
    const int wr = wave >> 1, wc = wave & 1;
    const int row_base = blockIdx.x * 128 + wr * 64;
    const int col_base = wc * 64;

    f32x4 acc[4][4] = {};

    for (int h = 0; h < K / 128; ++h) {
        for (int c = tid; c < 128 * 16; c += 256) {
            const int n = c >> 4;
            const int ko = (c & 15) * 8;
            *(uint4*)&sW[n * KP + ko] = *(const uint4*)&Wt[(size_t)n * K + h * 128 + ko];
        }
        __syncthreads();

#pragma unroll
        for (int ks = 0; ks < 4; ++ks) {
            const int kl = ks * 32 + quad * 8;
            const int kq = h * 128 + kl;
            short8 a[4];
#pragma unroll
            for (int rt = 0; rt < 4; ++rt) {
                int r = row_base + rt * 16 + nn;
                if (r >= M) r = M - 1;
                if constexpr (AF32) {
                    const float* ap = (const float*)A1v + (size_t)r * K + kq;
                    const float4 p = *(const float4*)ap;
                    const float4 q = *(const float4*)(ap + 4);
                    short8 t;
                    t[0] = bfbits(p.x); t[1] = bfbits(p.y);
                    t[2] = bfbits(p.z); t[3] = bfbits(p.w);
                    t[4] = bfbits(q.x); t[5] = bfbits(q.y);
                    t[6] = bfbits(q.z); t[7] = bfbits(q.w);
                    a[rt] = t;
                } else {
                    const __hip_bfloat16* base;
                    if (K1 == K || kq < K1)
                        base = (const __hip_bfloat16*)A1v + (size_t)r * K1 + kq;
                    else
                        base = A2 + (size_t)r * (K - K1) + (kq - K1);
                    a[rt] = *(const short8*)base;
                }
            }
#pragma unroll
            for (int ct = 0; ct < 4; ++ct) {
                const short8 b = *(const short8*)&sW[(col_base + ct * 16 + nn) * KP + kl];
#pragma unroll
                for (int rt = 0; rt < 4; ++rt)
                    acc[rt][ct] = __builtin_amdgcn_mfma_f32_16x16x32_bf16(
                        a[rt], b, acc[rt][ct], 0, 0, 0);
            }
        }
        __syncthreads();
    }

    float bs[4];
#pragma unroll
    for (int ct = 0; ct < 4; ++ct) bs[ct] = bias[col_base + ct * 16 + nn];

#pragma unroll
    for (int rt = 0; rt < 4; ++rt) {
#pragma unroll
        for (int i = 0; i < 4; ++i) {
            const int r = row_base + rt * 16 + quad * 4 + i;
            if (r < M) {
#pragma unroll
                for (int ct = 0; ct < 4; ++ct) {
                    float v = acc[rt][ct][i] + bs[ct];
                    if (act) v = sigmoidf_(v);
                    C[(size_t)r * 128 + col_base + ct * 16 + nn] = __float2bfloat16(v);
                }
            }
        }
    }
}

// ---------------------------------------------------------------------------
// MFMA output GEMM: out(M x 40) = X(M x 128 bf16) @ W + b, fp32 out.
// ---------------------------------------------------------------------------
__global__ __launch_bounds__(256) void out_gemm_mfma(
    const __hip_bfloat16* __restrict__ X,
    const __hip_bfloat16* __restrict__ Wt,   // 48 x 128 bf16 (n-major, padded)
    const float* __restrict__ b, float* __restrict__ out, int M)
{
    constexpr int KP = 136;
    __shared__ __hip_bfloat16 sW[48 * KP];
    __shared__ float sB[48];

    const int tid = threadIdx.x;
    for (int c = tid; c < 48 * 16; c += 256) {
        const int n = c >> 4, ko = (c & 15) * 8;
        *(uint4*)&sW[n * KP + ko] = *(const uint4*)&Wt[n * 128 + ko];
    }
    if (tid < 48) sB[tid] = (tid < 40) ? b[tid] : 0.0f;
    __syncthreads();

    const int wave = tid >> 6, lane = tid & 63;
    const int quad = lane >> 4, nn = lane & 15;
    const int row0 = blockIdx.x * 64 + wave * 16;

    f32x4 acc[3] = {};
#pragma unroll
    for (int ks = 0; ks < 4; ++ks) {
        int r = row0 + nn;
        if (r >= M) r = M - 1;
        const short8 a = *(const short8*)(X + (size_t)r * 128 + ks * 32 + quad * 8);
#pragma unroll
        for (int ct = 0; ct < 3; ++ct) {
            const short8 bf = *(const short8*)&sW[(ct * 16 + nn) * KP + ks * 32 + quad * 8];
            acc[ct] = __builtin_amdgcn_mfma_f32_16x16x32_bf16(a, bf, acc[ct], 0, 0, 0);
        }
    }
#pragma unroll
    for (int ct = 0; ct < 3; ++ct) {
        const int c = ct * 16 + nn;
#pragma unroll
        for (int i = 0; i < 4; ++i) {
            const int r = row0 + quad * 4 + i;
            if (r < M && c < 40) out[(size_t)r * 40 + c] = acc[ct][i] + sB[c];
        }
    }
}

// ---------------------------------------------------------------------------
// Weight prep: fp32 -> bf16 transposed Wt[n][k] for enc/m0/m1/out.
// ---------------------------------------------------------------------------
__global__ __launch_bounds__(256) void wprep_kernel(
    const float* __restrict__ We, const float* __restrict__ Wm0,
    const float* __restrict__ Wm1, const float* __restrict__ Wout,
    __hip_bfloat16* __restrict__ Wt_enc, __hip_bfloat16* __restrict__ Wt_m0,
    __hip_bfloat16* __restrict__ Wt_m1, __hip_bfloat16* __restrict__ Wt_out)
{
    const int i = blockIdx.x * 256 + threadIdx.x;  // 0..137215
    if (i < 32768) {
        const int n = i >> 8, k = i & 255;
        Wt_enc[n * 256 + k] = __float2bfloat16(We[k * 128 + n]);
    } else if (i < 65536) {
        int j = i - 32768; const int l = j >> 14; j &= 16383;
        const int n = j >> 7, k = j & 127;
        Wt_m0[l * 16384 + n * 128 + k] = __float2bfloat16(Wm0[l * 16384 + k * 128 + n]);
    } else if (i < 131072) {
        int j = i - 65536; const int l = j >> 15; j &= 32767;
        const int n = j >> 8, k = j & 255;
        Wt_m1[l * 32768 + n * 256 + k] = __float2bfloat16(Wm1[l * 32768 + k * 128 + n]);
    } else {
        const int j = i - 131072;
        const int n = j >> 7, k = j & 127;
        Wt_out[n * 128 + k] = (n < 40) ? __float2bfloat16(Wout[k * 40 + n])
                                       : __float2bfloat16(0.0f);
    }
}

// ---------------------------------------------------------------------------
// CSR build (atomic-free fill: hist captures per-edge rank)
// ---------------------------------------------------------------------------
__global__ __launch_bounds__(256) void zero_int_kernel(int* __restrict__ p, int n)
{
    const int i = blockIdx.x * 256 + threadIdx.x;
    if (i < n) p[i] = 0;
}

__global__ __launch_bounds__(256) void hist_kernel(
    const int* __restrict__ he_idx, const int* __restrict__ node_idx,
    int* __restrict__ he_cnt, int* __restrict__ node_cnt,
    int* __restrict__ he_rank, int* __restrict__ node_rank, int n)
{
    const int i = blockIdx.x * 256 + threadIdx.x;
    if (i < n) {
        he_rank[i] = atomicAdd(&he_cnt[he_idx[i]], 1);
        node_rank[i] = atomicAdd(&node_cnt[node_idx[i]], 1);
    }
}

// exclusive scan over combined [he_cnt | node_cnt] (node part adj by -N_INC)
__global__ __launch_bounds__(256) void scan1_kernel(
    int* __restrict__ data, int* __restrict__ bsums, int n)
{
    __shared__ int s[256];
    const int t = threadIdx.x;
    const int base = blockIdx.x * 1024 + t * 4;
    int4 v = make_int4(0, 0, 0, 0);
    if (base < n) v = *(const int4*)(data + base);
    s[t] = v.x + v.y + v.z + v.w;
    __syncthreads();
    for (int d = 1; d < 256; d <<= 1) {
        const int u = (t >= d) ? s[t - d] : 0;
        __syncthreads();
        s[t] += u;
        __syncthreads();
    }
    if (t == 255) bsums[blockIdx.x] = s[255];
    int e = t ? s[t - 1] : 0;
    if (base < n) {
        int4 o;
        o.x = e; e += v.x; o.y = e; e += v.y; o.z = e; e += v.z; o.w = e;
        *(int4*)(data + base) = o;
    }
}

__global__ __launch_bounds__(256) void scan2_kernel(int* __restrict__ bsums, int nb)
{
    __shared__ int s[256];
    const int t = threadIdx.x;
    const int v = (t < nb) ? bsums[t] : 0;
    s[t] = v;
    __syncthreads();
    for (int d = 1; d < 256; d <<= 1) {
        const int u = (t >= d) ? s[t - d] : 0;
        __syncthreads();
        s[t] += u;
        __syncthreads();
    }
    if (t < nb) bsums[t] = s[t] - v;
}

__global__ __launch_bounds__(256) void scan3_kernel(
    int* __restrict__ data, const int* __restrict__ bsums, int n)
{
    const int base = blockIdx.x * 1024 + threadIdx.x * 4;
    if (base >= n) return;
    const int adj = bsums[blockIdx.x] - ((base >= N_HE) ? N_INC : 0);
    int4 v = *(int4*)(data + base);
    v.x += adj; v.y += adj; v.z += adj; v.w += adj;
    *(int4*)(data + base) = v;
}

// fill packed edges at off[dest]+rank[e] — NO atomics
__global__ __launch_bounds__(256) void fill_kernel(
    const int* __restrict__ node_idx, const int* __restrict__ he_idx,
    const float* __restrict__ vals,
    const int* __restrict__ he_off, const int* __restrict__ node_off,
    const int* __restrict__ he_rank, const int* __restrict__ node_rank,
    int2* __restrict__ he_edge, int2* __restrict__ node_edge, int n)
{
    const int e = blockIdx.x * 256 + threadIdx.x;
    if (e >= n) return;
    const int hn = he_idx[e], nd = node_idx[e];
    const int vb = __float_as_int(vals[e]);
    he_edge[he_off[hn] + he_rank[e]] = make_int2(nd, vb);
    node_edge[node_off[nd] + node_rank[e]] = make_int2(hn, vb);
}

// ---------------------------------------------------------------------------
// Fused he-gather (2 edges/wave-iter): agg = sum val*m0[src];
// writes m0_he AND x1_next = sigmoid(x1_cur + agg).
// Half-wave h handles edge e+h; lane&31 owns 4 cols (8B). Offsets EXCLUSIVE.
// ---------------------------------------------------------------------------
__global__ __launch_bounds__(256) void gather_he_kernel(
    const __hip_bfloat16* __restrict__ msrc,
    const __hip_bfloat16* __restrict__ x1cur,
    __hip_bfloat16* __restrict__ m0_he,
    __hip_bfloat16* __restrict__ x1next,
    const int* __restrict__ off, const int2* __restrict__ edges, int n_seg)
{
    const int wave = threadIdx.x >> 6;
    const int lane = threadIdx.x & 63;
    const int row = blockIdx.x * 4 + wave;
    if (row >= n_seg) return;
    const int start = off[row];
    const int end = (row + 1 < n_seg) ? off[row + 1] : N_INC;
    const int half = lane >> 5;
    const int l32 = lane & 31;
    float a0 = 0.f, a1 = 0.f, a2 = 0.f, a3 = 0.f;
    const unsigned short* s16 = (const unsigned short*)msrc;
    for (int e = start; e < end; e += 2) {
        const int ee = e + half;
        const int2 ed = (ee < end) ? edges[ee] : make_int2(0, 0);
        const float v = __int_as_float(ed.y);
        const uint2 u = *(const uint2*)(s16 + (size_t)ed.x * 128 + l32 * 4);
        a0 += bf_lo(u.x) * v; a1 += bf_hi(u.x) * v;
        a2 += bf_lo(u.y) * v; a3 += bf_hi(u.y) * v;
    }
    a0 += __shfl_xor(a0, 32); a1 += __shfl_xor(a1, 32);
    a2 += __shfl_xor(a2, 32); a3 += __shfl_xor(a3, 32);
    if (half == 0) {
        const size_t o = (size_t)row * 128 + l32 * 4;
        uint2 mg; mg.x = bfpack(a0, a1); mg.y = bfpack(a2, a3);
        *(uint2*)((unsigned short*)m0_he + o) = mg;
        const uint2 xu = *(const uint2*)((const unsigned short*)x1cur + o);
        uint2 r;
        r.x = bfpack(sigmoidf_(bf_lo(xu.x) + a0), sigmoidf_(bf_hi(xu.x) + a1));
        r.y = bfpack(sigmoidf_(bf_lo(xu.y) + a2), sigmoidf_(bf_hi(xu.y) + a3));
        *(uint2*)((unsigned short*)x1next + o) = r;
    }
}

// ---------------------------------------------------------------------------
// Fused node-gather (2 edges/wave-iter): x0 = sigmoid(x0 + agg) in place.
// ---------------------------------------------------------------------------
__global__ __launch_bounds__(256) void gather_node_kernel(
    const __hip_bfloat16* __restrict__ msrc,
    __hip_bfloat16* __restrict__ x0,
    const int* __restrict__ off, const int2* __restrict__ edges, int n_seg)
{
    const int wave = threadIdx.x >> 6;
    const int lane = threadIdx.x & 63;
    const int row = blockIdx.x * 4 + wave;
    if (row >= n_seg) return;
    const int start = off[row];
    const int end = (row + 1 < n_seg) ? off[row + 1] : N_INC;
    const int half = lane >> 5;
    const int l32 = lane & 31;
    float a0 = 0.f, a1 = 0.f, a2 = 0.f, a3 = 0.f;
    const unsigned short* s16 = (const unsigned short*)msrc;
    for (int e = start; e < end; e += 2) {
        const int ee = e + half;
        const int2 ed = (ee < end) ? edges[ee] : make_int2(0, 0);
        const float v = __int_as_float(ed.y);
        const uint2 u = *(const uint2*)(s16 + (size_t)ed.x * 128 + l32 * 4);
        a0 += bf_lo(u.x) * v; a1 += bf_hi(u.x) * v;
        a2 += bf_lo(u.y) * v; a3 += bf_hi(u.y) * v;
    }
    a0 += __shfl_xor(a0, 32); a1 += __shfl_xor(a1, 32);
    a2 += __shfl_xor(a2, 32); a3 += __shfl_xor(a3, 32);
    if (half == 0) {
        const size_t o = (size_t)row * 128 + l32 * 4;
        uint2* px = (uint2*)((unsigned short*)x0 + o);
        const uint2 xu = *px;
        uint2 r;
        r.x = bfpack(sigmoidf_(bf_lo(xu.x) + a0), sigmoidf_(bf_hi(xu.x) + a1));
        r.y = bfpack(sigmoidf_(bf_lo(xu.y) + a2), sigmoidf_(bf_hi(xu.y) + a3));
        *px = r;
    }
}

// ---------------------------------------------------------------------------
extern "C" void kernel_launch(void* const* d_in, const int* in_sizes, int n_in,
                              void* d_out, int out_size, void* d_ws, size_t ws_size,
                              hipStream_t stream)
{
    const float* x0_in   = (const float*)d_in[0];
    const float* x1_in   = (const float*)d_in[1];
    const int*   node_idx = (const int*)d_in[2];
    const int*   he_idx   = (const int*)d_in[3];
    const float* inc_vals = (const float*)d_in[4];
    const float* W_enc   = (const float*)d_in[5];
    const float* b_enc   = (const float*)d_in[6];
    const float* W_msg0  = (const float*)d_in[7];
    const float* b_msg0  = (const float*)d_in[8];
    const float* W_msg1  = (const float*)d_in[9];
    const float* b_msg1  = (const float*)d_in[10];
    const float* W_out   = (const float*)d_in[11];
    const float* b_out   = (const float*)d_in[12];
    float* out = (float*)d_out;

    __hip_bfloat16* x0h    = (__hip_bfloat16*)d_ws;         // 12,800,000
    __hip_bfloat16* x1a    = x0h + 12800000;                //  6,400,000
    __hip_bfloat16* x1b    = x1a + 6400000;                 //  6,400,000
    __hip_bfloat16* mbuf   = x1b + 6400000;                 // 12,800,000
    __hip_bfloat16* m0_he  = mbuf + 12800000;               //  6,400,000
    __hip_bfloat16* Wt_enc = m0_he + 6400000;               // 32768
    __hip_bfloat16* Wt_m0  = Wt_enc + 32768;                // 32768
    __hip_bfloat16* Wt_m1  = Wt_m0 + 32768;                 // 65536
    __hip_bfloat16* Wt_out = Wt_m1 + 65536;                 // 6144
    int*  he_off    = (int*)(Wt_out + 6144);
    int*  node_off  = he_off + N_HE;
    int*  bsums     = node_off + N_NODES;                   // 256
    int*  he_rank   = bsums + 256;                          // 600k
    int*  node_rank = he_rank + N_INC;                      // 600k
    int2* he_edge   = (int2*)(node_rank + N_INC);
    int2* node_edge = he_edge + N_INC;

    // ---- CSR build ----
    zero_int_kernel<<<(N_HE + N_NODES + 255) / 256, 256, 0, stream>>>(
        he_off, N_HE + N_NODES);
    hist_kernel<<<(N_INC + 255) / 256, 256, 0, stream>>>(
        he_idx, node_idx, he_off, node_off, he_rank, node_rank, N_INC);
    const int scan_n = N_HE + N_NODES;
    const int scan_blocks = (scan_n + 1023) / 1024;          // 147
    scan1_kernel<<<scan_blocks, 256, 0, stream>>>(he_off, bsums, scan_n);
    scan2_kernel<<<1, 256, 0, stream>>>(bsums, scan_blocks);
    scan3_kernel<<<scan_blocks, 256, 0, stream>>>(he_off, bsums, scan_n);
    fill_kernel<<<(N_INC + 255) / 256, 256, 0, stream>>>(
        node_idx, he_idx, inc_vals, he_off, node_off, he_rank, node_rank,
        he_edge, node_edge, N_INC);

    // ---- weight prep ----
    wprep_kernel<<<536, 256, 0, stream>>>(W_enc, W_msg0, W_msg1, W_out,
                                          Wt_enc, Wt_m0, Wt_m1, Wt_out);

    // ---- encode ----
    gemm_mfma<256, 256, true><<<(N_NODES + 127) / 128, 256, 0, stream>>>(
        x0_in, nullptr, Wt_enc, b_enc, x0h, N_NODES, 0);
    gemm_mfma<256, 256, true><<<(N_HE + 127) / 128, 256, 0, stream>>>(
        x1_in, nullptr, Wt_enc, b_enc, x1a, N_HE, 0);

    __hip_bfloat16* x1cur = x1a;
    __hip_bfloat16* x1nxt = x1b;
    for (int l = 0; l < 2; ++l) {
        gemm_mfma<128, 128, false><<<(N_NODES + 127) / 128, 256, 0, stream>>>(
            x0h, nullptr, Wt_m0 + (size_t)l * 16384,
            b_msg0 + (size_t)l * 128, mbuf, N_NODES, 1);
        gather_he_kernel<<<(N_HE + 3) / 4, 256, 0, stream>>>(
            mbuf, x1cur, m0_he, x1nxt, he_off, he_edge, N_HE);
        gemm_mfma<256, 128, false><<<(N_HE + 127) / 128, 256, 0, stream>>>(
            x1cur, m0_he, Wt_m1 + (size_t)l * 32768,
            b_msg1 + (size_t)l * 128, mbuf, N_HE, 1);
        gather_node_kernel<<<(N_NODES + 3) / 4, 256, 0, stream>>>(
            mbuf, x0h, node_off, node_edge, N_NODES);
        __hip_bfloat16* t = x1cur; x1cur = x1nxt; x1nxt = t;
    }

    out_gemm_mfma<<<(N_NODES + 63) / 64, 256, 0, stream>>>(
        x0h, Wt_out, b_out, out, N_NODES);
}

// Round 7
// 664.691 us; speedup vs baseline: 7.3174x; 1.0019x over previous
//
#include <hip/hip_runtime.h>
#include <hip/hip_bf16.h>
#include <math.h>

#define N_NODES 100000
#define N_HE    50000
#define N_INC   600000
#define D_IN    256
#define D_H     128
#define N_CLASSES 40

typedef __attribute__((ext_vector_type(8))) short short8;
typedef __attribute__((ext_vector_type(4))) float f32x4;

__device__ __forceinline__ float sigmoidf_(float x) {
    return 1.0f / (1.0f + expf(-x));
}

__device__ __forceinline__ short bfbits(float f) {
    __hip_bfloat16 h = __float2bfloat16(f);
    return *reinterpret_cast<short*>(&h);
}

__device__ __forceinline__ float bf_lo(unsigned u) { return __uint_as_float(u << 16); }
__device__ __forceinline__ float bf_hi(unsigned u) { return __uint_as_float(u & 0xffff0000u); }
__device__ __forceinline__ unsigned bfpack(float a, float b) {
    return (unsigned)(unsigned short)bfbits(a) | ((unsigned)(unsigned short)bfbits(b) << 16);
}

// ---------------------------------------------------------------------------
// MFMA GEMM: C(M x 128) = act( [A1|A2] @ W + bias ), bf16 inputs, fp32 acc.
// Block = 256 thr (4 waves 2x2), BM=128, BN=128, wave tile 64x64.
// Epilogue: stage C in LDS (reuse sW, stride 136 -> 2-way only), then
// cooperative full-line uint4 stores (no write-allocate fetch).
// ---------------------------------------------------------------------------
template<int K, int K1, bool AF32>
__global__ __launch_bounds__(256) void gemm_mfma(
    const void* __restrict__ A1v,
    const __hip_bfloat16* __restrict__ A2,
    const __hip_bfloat16* __restrict__ Wt,   // 128 x K bf16, transposed
    const float* __restrict__ bias,
    __hip_bfloat16* __restrict__ C,          // M x 128 bf16
    int M, int act)
{
    constexpr int KP = 136;
    __shared__ __hip_bfloat16 sW[128 * KP];  // 34816 B; reused for C staging

    const int tid = threadIdx.x;
    const int wave = tid >> 6, lane = tid & 63;
    const int quad = lane >> 4, nn = lane & 15;
    const int wr = wave >> 1, wc = wave & 1;
    const int row_base = blockIdx.x * 128 + wr * 64;
    const int col_base = wc * 64;

    f32x4 acc[4][4] = {};

    for (int h = 0; h < K / 128; ++h) {
        for (int c = tid; c < 128 * 16; c += 256) {
            const int n = c >> 4;
            const int ko = (c & 15) * 8;
            *(uint4*)&sW[n * KP + ko] = *(const uint4*)&Wt[(size_t)n * K + h * 128 + ko];
        }
        __syncthreads();

#pragma unroll
        for (int ks = 0; ks < 4; ++ks) {
            const int kl = ks * 32 + quad * 8;
            const int kq = h * 128 + kl;
            short8 a[4];
#pragma unroll
            for (int rt = 0; rt < 4; ++rt) {
                int r = row_base + rt * 16 + nn;
                if (r >= M) r = M - 1;
                if constexpr (AF32) {
                    const float* ap = (const float*)A1v + (size_t)r * K + kq;
                    const float4 p = *(const float4*)ap;
                    const float4 q = *(const float4*)(ap + 4);
                    short8 t;
                    t[0] = bfbits(p.x); t[1] = bfbits(p.y);
                    t[2] = bfbits(p.z); t[3] = bfbits(p.w);
                    t[4] = bfbits(q.x); t[5] = bfbits(q.y);
                    t[6] = bfbits(q.z); t[7] = bfbits(q.w);
                    a[rt] = t;
                } else {
                    const __hip_bfloat16* base;
                    if (K1 == K || kq < K1)
                        base = (const __hip_bfloat16*)A1v + (size_t)r * K1 + kq;
                    else
                        base = A2 + (size_t)r * (K - K1) + (kq - K1);
                    a[rt] = *(const short8*)base;
                }
            }
#pragma unroll
            for (int ct = 0; ct < 4; ++ct) {
                const short8 b = *(const short8*)&sW[(col_base + ct * 16 + nn) * KP + kl];
#pragma unroll
                for (int rt = 0; rt < 4; ++rt)
                    acc[rt][ct] = __builtin_amdgcn_mfma_f32_16x16x32_bf16(
                        a[rt], b, acc[rt][ct], 0, 0, 0);
            }
        }
        __syncthreads();   // also protects sW reuse below on last iteration
    }

    float bs[4];
#pragma unroll
    for (int ct = 0; ct < 4; ++ct) bs[ct] = bias[col_base + ct * 16 + nn];

    // ---- stage C tile into LDS (bf16, stride KP=136) ----
    unsigned short* sC = (unsigned short*)sW;
#pragma unroll
    for (int rt = 0; rt < 4; ++rt) {
#pragma unroll
        for (int i = 0; i < 4; ++i) {
            const int R = wr * 64 + rt * 16 + quad * 4 + i;
#pragma unroll
            for (int ct = 0; ct < 4; ++ct) {
                float v = acc[rt][ct][i] + bs[ct];
                if (act) v = sigmoidf_(v);
                sC[R * KP + col_base + ct * 16 + nn] = (unsigned short)bfbits(v);
            }
        }
    }
    __syncthreads();

    // ---- cooperative coalesced store: thread t -> row t/2, half t&1 ----
    // each half-row = 64 bf16 = 128 B = 8 uint4
    {
        const int row = tid >> 1, half = tid & 1;
        const int gr = blockIdx.x * 128 + row;
        if (gr < M) {
            const unsigned short* srcp = sC + row * KP + half * 64;
            uint4* dstp = (uint4*)(C + (size_t)gr * 128 + half * 64);
#pragma unroll
            for (int j = 0; j < 8; ++j) dstp[j] = *(const uint4*)(srcp + j * 8);
        }
    }
}

// ---------------------------------------------------------------------------
// MFMA output GEMM: out(M x 40) = X(M x 128 bf16) @ W + b, fp32 out.
// Epilogue staged via LDS (stride 44 fp32) -> coalesced float4 stores.
// ---------------------------------------------------------------------------
__global__ __launch_bounds__(256) void out_gemm_mfma(
    const __hip_bfloat16* __restrict__ X,
    const __hip_bfloat16* __restrict__ Wt,   // 48 x 128 bf16 (n-major, padded)
    const float* __restrict__ b, float* __restrict__ out, int M)
{
    constexpr int KP = 136;
    __shared__ __hip_bfloat16 sW[48 * KP];
    __shared__ float sB[48];
    __shared__ float sO[64 * 44];            // 11264 B

    const int tid = threadIdx.x;
    for (int c = tid; c < 48 * 16; c += 256) {
        const int n = c >> 4, ko = (c & 15) * 8;
        *(uint4*)&sW[n * KP + ko] = *(const uint4*)&Wt[n * 128 + ko];
    }
    if (tid < 48) sB[tid] = (tid < 40) ? b[tid] : 0.0f;
    __syncthreads();

    const int wave = tid >> 6, lane = tid & 63;
    const int quad = lane >> 4, nn = lane & 15;
    const int row0 = blockIdx.x * 64 + wave * 16;

    f32x4 acc[3] = {};
#pragma unroll
    for (int ks = 0; ks < 4; ++ks) {
        int r = row0 + nn;
        if (r >= M) r = M - 1;
        const short8 a = *(const short8*)(X + (size_t)r * 128 + ks * 32 + quad * 8);
#pragma unroll
        for (int ct = 0; ct < 3; ++ct) {
            const short8 bf = *(const short8*)&sW[(ct * 16 + nn) * KP + ks * 32 + quad * 8];
            acc[ct] = __builtin_amdgcn_mfma_f32_16x16x32_bf16(a, bf, acc[ct], 0, 0, 0);
        }
    }

    // stage into LDS
#pragma unroll
    for (int ct = 0; ct < 3; ++ct) {
        const int c = ct * 16 + nn;
        if (c < 40) {
#pragma unroll
            for (int i = 0; i < 4; ++i) {
                const int rl = wave * 16 + quad * 4 + i;
                sO[rl * 44 + c] = acc[ct][i] + sB[c];
            }
        }
    }
    __syncthreads();

    // cooperative store: 64 rows x 10 float4
    for (int c = tid; c < 640; c += 256) {
        const int row = c / 10, ch = c % 10;
        const int gr = blockIdx.x * 64 + row;
        if (gr < M)
            *(float4*)(out + (size_t)gr * 40 + ch * 4) =
                *(const float4*)(sO + row * 44 + ch * 4);
    }
}

// ---------------------------------------------------------------------------
// Weight prep: fp32 -> bf16 transposed Wt[n][k] for enc/m0/m1/out.
// ---------------------------------------------------------------------------
__global__ __launch_bounds__(256) void wprep_kernel(
    const float* __restrict__ We, const float* __restrict__ Wm0,
    const float* __restrict__ Wm1, const float* __restrict__ Wout,
    __hip_bfloat16* __restrict__ Wt_enc, __hip_bfloat16* __restrict__ Wt_m0,
    __hip_bfloat16* __restrict__ Wt_m1, __hip_bfloat16* __restrict__ Wt_out)
{
    const int i = blockIdx.x * 256 + threadIdx.x;  // 0..137215
    if (i < 32768) {
        const int n = i >> 8, k = i & 255;
        Wt_enc[n * 256 + k] = __float2bfloat16(We[k * 128 + n]);
    } else if (i < 65536) {
        int j = i - 32768; const int l = j >> 14; j &= 16383;
        const int n = j >> 7, k = j & 127;
        Wt_m0[l * 16384 + n * 128 + k] = __float2bfloat16(Wm0[l * 16384 + k * 128 + n]);
    } else if (i < 131072) {
        int j = i - 65536; const int l = j >> 15; j &= 32767;
        const int n = j >> 8, k = j & 255;
        Wt_m1[l * 32768 + n * 256 + k] = __float2bfloat16(Wm1[l * 32768 + k * 128 + n]);
    } else {
        const int j = i - 131072;
        const int n = j >> 7, k = j & 127;
        Wt_out[n * 128 + k] = (n < 40) ? __float2bfloat16(Wout[k * 40 + n])
                                       : __float2bfloat16(0.0f);
    }
}

// ---------------------------------------------------------------------------
// CSR build (atomic-free fill: hist captures per-edge rank)
// ---------------------------------------------------------------------------
__global__ __launch_bounds__(256) void zero_int_kernel(int* __restrict__ p, int n)
{
    const int i = blockIdx.x * 256 + threadIdx.x;
    if (i < n) p[i] = 0;
}

__global__ __launch_bounds__(256) void hist_kernel(
    const int* __restrict__ he_idx, const int* __restrict__ node_idx,
    int* __restrict__ he_cnt, int* __restrict__ node_cnt,
    int* __restrict__ he_rank, int* __restrict__ node_rank, int n)
{
    const int i = blockIdx.x * 256 + threadIdx.x;
    if (i < n) {
        he_rank[i] = atomicAdd(&he_cnt[he_idx[i]], 1);
        node_rank[i] = atomicAdd(&node_cnt[node_idx[i]], 1);
    }
}

__global__ __launch_bounds__(256) void scan1_kernel(
    int* __restrict__ data, int* __restrict__ bsums, int n)
{
    __shared__ int s[256];
    const int t = threadIdx.x;
    const int base = blockIdx.x * 1024 + t * 4;
    int4 v = make_int4(0, 0, 0, 0);
    if (base < n) v = *(const int4*)(data + base);
    s[t] = v.x + v.y + v.z + v.w;
    __syncthreads();
    for (int d = 1; d < 256; d <<= 1) {
        const int u = (t >= d) ? s[t - d] : 0;
        __syncthreads();
        s[t] += u;
        __syncthreads();
    }
    if (t == 255) bsums[blockIdx.x] = s[255];
    int e = t ? s[t - 1] : 0;
    if (base < n) {
        int4 o;
        o.x = e; e += v.x; o.y = e; e += v.y; o.z = e; e += v.z; o.w = e;
        *(int4*)(data + base) = o;
    }
}

__global__ __launch_bounds__(256) void scan2_kernel(int* __restrict__ bsums, int nb)
{
    __shared__ int s[256];
    const int t = threadIdx.x;
    const int v = (t < nb) ? bsums[t] : 0;
    s[t] = v;
    __syncthreads();
    for (int d = 1; d < 256; d <<= 1) {
        const int u = (t >= d) ? s[t - d] : 0;
        __syncthreads();
        s[t] += u;
        __syncthreads();
    }
    if (t < nb) bsums[t] = s[t] - v;
}

__global__ __launch_bounds__(256) void scan3_kernel(
    int* __restrict__ data, const int* __restrict__ bsums, int n)
{
    const int base = blockIdx.x * 1024 + threadIdx.x * 4;
    if (base >= n) return;
    const int adj = bsums[blockIdx.x] - ((base >= N_HE) ? N_INC : 0);
    int4 v = *(int4*)(data + base);
    v.x += adj; v.y += adj; v.z += adj; v.w += adj;
    *(int4*)(data + base) = v;
}

// fill packed edges at off[dest]+rank[e] — NO atomics
__global__ __launch_bounds__(256) void fill_kernel(
    const int* __restrict__ node_idx, const int* __restrict__ he_idx,
    const float* __restrict__ vals,
    const int* __restrict__ he_off, const int* __restrict__ node_off,
    const int* __restrict__ he_rank, const int* __restrict__ node_rank,
    int2* __restrict__ he_edge, int2* __restrict__ node_edge, int n)
{
    const int e = blockIdx.x * 256 + threadIdx.x;
    if (e >= n) return;
    const int hn = he_idx[e], nd = node_idx[e];
    const int vb = __float_as_int(vals[e]);
    he_edge[he_off[hn] + he_rank[e]] = make_int2(nd, vb);
    node_edge[node_off[nd] + node_rank[e]] = make_int2(hn, vb);
}

// ---------------------------------------------------------------------------
// Fused he-gather (2 edges/wave-iter): agg = sum val*m0[src];
// writes m0_he AND x1_next = sigmoid(x1_cur + agg). Offsets EXCLUSIVE.
// ---------------------------------------------------------------------------
__global__ __launch_bounds__(256) void gather_he_kernel(
    const __hip_bfloat16* __restrict__ msrc,
    const __hip_bfloat16* __restrict__ x1cur,
    __hip_bfloat16* __restrict__ m0_he,
    __hip_bfloat16* __restrict__ x1next,
    const int* __restrict__ off, const int2* __restrict__ edges, int n_seg)
{
    const int wave = threadIdx.x >> 6;
    const int lane = threadIdx.x & 63;
    const int row = blockIdx.x * 4 + wave;
    if (row >= n_seg) return;
    const int start = off[row];
    const int end = (row + 1 < n_seg) ? off[row + 1] : N_INC;
    const int half = lane >> 5;
    const int l32 = lane & 31;
    float a0 = 0.f, a1 = 0.f, a2 = 0.f, a3 = 0.f;
    const unsigned short* s16 = (const unsigned short*)msrc;
    for (int e = start; e < end; e += 2) {
        const int ee = e + half;
        const int2 ed = (ee < end) ? edges[ee] : make_int2(0, 0);
        const float v = __int_as_float(ed.y);
        const uint2 u = *(const uint2*)(s16 + (size_t)ed.x * 128 + l32 * 4);
        a0 += bf_lo(u.x) * v; a1 += bf_hi(u.x) * v;
        a2 += bf_lo(u.y) * v; a3 += bf_hi(u.y) * v;
    }
    a0 += __shfl_xor(a0, 32); a1 += __shfl_xor(a1, 32);
    a2 += __shfl_xor(a2, 32); a3 += __shfl_xor(a3, 32);
    if (half == 0) {
        const size_t o = (size_t)row * 128 + l32 * 4;
        uint2 mg; mg.x = bfpack(a0, a1); mg.y = bfpack(a2, a3);
        *(uint2*)((unsigned short*)m0_he + o) = mg;
        const uint2 xu = *(const uint2*)((const unsigned short*)x1cur + o);
        uint2 r;
        r.x = bfpack(sigmoidf_(bf_lo(xu.x) + a0), sigmoidf_(bf_hi(xu.x) + a1));
        r.y = bfpack(sigmoidf_(bf_lo(xu.y) + a2), sigmoidf_(bf_hi(xu.y) + a3));
        *(uint2*)((unsigned short*)x1next + o) = r;
    }
}

// ---------------------------------------------------------------------------
// Fused node-gather (2 edges/wave-iter): x0 = sigmoid(x0 + agg) in place.
// ---------------------------------------------------------------------------
__global__ __launch_bounds__(256) void gather_node_kernel(
    const __hip_bfloat16* __restrict__ msrc,
    __hip_bfloat16* __restrict__ x0,
    const int* __restrict__ off, const int2* __restrict__ edges, int n_seg)
{
    const int wave = threadIdx.x >> 6;
    const int lane = threadIdx.x & 63;
    const int row = blockIdx.x * 4 + wave;
    if (row >= n_seg) return;
    const int start = off[row];
    const int end = (row + 1 < n_seg) ? off[row + 1] : N_INC;
    const int half = lane >> 5;
    const int l32 = lane & 31;
    float a0 = 0.f, a1 = 0.f, a2 = 0.f, a3 = 0.f;
    const unsigned short* s16 = (const unsigned short*)msrc;
    for (int e = start; e < end; e += 2) {
        const int ee = e + half;
        const int2 ed = (ee < end) ? edges[ee] : make_int2(0, 0);
        const float v = __int_as_float(ed.y);
        const uint2 u = *(const uint2*)(s16 + (size_t)ed.x * 128 + l32 * 4);
        a0 += bf_lo(u.x) * v; a1 += bf_hi(u.x) * v;
        a2 += bf_lo(u.y) * v; a3 += bf_hi(u.y) * v;
    }
    a0 += __shfl_xor(a0, 32); a1 += __shfl_xor(a1, 32);
    a2 += __shfl_xor(a2, 32); a3 += __shfl_xor(a3, 32);
    if (half == 0) {
        const size_t o = (size_t)row * 128 + l32 * 4;
        uint2* px = (uint2*)((unsigned short*)x0 + o);
        const uint2 xu = *px;
        uint2 r;
        r.x = bfpack(sigmoidf_(bf_lo(xu.x) + a0), sigmoidf_(bf_hi(xu.x) + a1));
        r.y = bfpack(sigmoidf_(bf_lo(xu.y) + a2), sigmoidf_(bf_hi(xu.y) + a3));
        *px = r;
    }
}

// ---------------------------------------------------------------------------
extern "C" void kernel_launch(void* const* d_in, const int* in_sizes, int n_in,
                              void* d_out, int out_size, void* d_ws, size_t ws_size,
                              hipStream_t stream)
{
    const float* x0_in   = (const float*)d_in[0];
    const float* x1_in   = (const float*)d_in[1];
    const int*   node_idx = (const int*)d_in[2];
    const int*   he_idx   = (const int*)d_in[3];
    const float* inc_vals = (const float*)d_in[4];
    const float* W_enc   = (const float*)d_in[5];
    const float* b_enc   = (const float*)d_in[6];
    const float* W_msg0  = (const float*)d_in[7];
    const float* b_msg0  = (const float*)d_in[8];
    const float* W_msg1  = (const float*)d_in[9];
    const float* b_msg1  = (const float*)d_in[10];
    const float* W_out   = (const float*)d_in[11];
    const float* b_out   = (const float*)d_in[12];
    float* out = (float*)d_out;

    __hip_bfloat16* x0h    = (__hip_bfloat16*)d_ws;         // 12,800,000
    __hip_bfloat16* x1a    = x0h + 12800000;                //  6,400,000
    __hip_bfloat16* x1b    = x1a + 6400000;                 //  6,400,000
    __hip_bfloat16* mbuf   = x1b + 6400000;                 // 12,800,000
    __hip_bfloat16* m0_he  = mbuf + 12800000;               //  6,400,000
    __hip_bfloat16* Wt_enc = m0_he + 6400000;               // 32768
    __hip_bfloat16* Wt_m0  = Wt_enc + 32768;                // 32768
    __hip_bfloat16* Wt_m1  = Wt_m0 + 32768;                 // 65536
    __hip_bfloat16* Wt_out = Wt_m1 + 65536;                 // 6144
    int*  he_off    = (int*)(Wt_out + 6144);
    int*  node_off  = he_off + N_HE;
    int*  bsums     = node_off + N_NODES;                   // 256
    int*  he_rank   = bsums + 256;                          // 600k
    int*  node_rank = he_rank + N_INC;                      // 600k
    int2* he_edge   = (int2*)(node_rank + N_INC);
    int2* node_edge = he_edge + N_INC;

    // ---- CSR build ----
    zero_int_kernel<<<(N_HE + N_NODES + 255) / 256, 256, 0, stream>>>(
        he_off, N_HE + N_NODES);
    hist_kernel<<<(N_INC + 255) / 256, 256, 0, stream>>>(
        he_idx, node_idx, he_off, node_off, he_rank, node_rank, N_INC);
    const int scan_n = N_HE + N_NODES;
    const int scan_blocks = (scan_n + 1023) / 1024;          // 147
    scan1_kernel<<<scan_blocks, 256, 0, stream>>>(he_off, bsums, scan_n);
    scan2_kernel<<<1, 256, 0, stream>>>(bsums, scan_blocks);
    scan3_kernel<<<scan_blocks, 256, 0, stream>>>(he_off, bsums, scan_n);
    fill_kernel<<<(N_INC + 255) / 256, 256, 0, stream>>>(
        node_idx, he_idx, inc_vals, he_off, node_off, he_rank, node_rank,
        he_edge, node_edge, N_INC);

    // ---- weight prep ----
    wprep_kernel<<<536, 256, 0, stream>>>(W_enc, W_msg0, W_msg1, W_out,
                                          Wt_enc, Wt_m0, Wt_m1, Wt_out);

    // ---- encode ----
    gemm_mfma<256, 256, true><<<(N_NODES + 127) / 128, 256, 0, stream>>>(
        x0_in, nullptr, Wt_enc, b_enc, x0h, N_NODES, 0);
    gemm_mfma<256, 256, true><<<(N_HE + 127) / 128, 256, 0, stream>>>(
        x1_in, nullptr, Wt_enc, b_enc, x1a, N_HE, 0);

    __hip_bfloat16* x1cur = x1a;
    __hip_bfloat16* x1nxt = x1b;
    for (int l = 0; l < 2; ++l) {
        gemm_mfma<128, 128, false><<<(N_NODES + 127) / 128, 256, 0, stream>>>(
            x0h, nullptr, Wt_m0 + (size_t)l * 16384,
            b_msg0 + (size_t)l * 128, mbuf, N_NODES, 1);
        gather_he_kernel<<<(N_HE + 3) / 4, 256, 0, stream>>>(
            mbuf, x1cur, m0_he, x1nxt, he_off, he_edge, N_HE);
        gemm_mfma<256, 128, false><<<(N_HE + 127) / 128, 256, 0, stream>>>(
            x1cur, m0_he, Wt_m1 + (size_t)l * 32768,
            b_msg1 + (size_t)l * 128, mbuf, N_HE, 1);
        gather_node_kernel<<<(N_NODES + 3) / 4, 256, 0, stream>>>(
            mbuf, x0h, node_off, node_edge, N_NODES);
        __hip_bfloat16* t = x1cur; x1cur = x1nxt; x1nxt = t;
    }

    out_gemm_mfma<<<(N_NODES + 63) / 64, 256, 0, stream>>>(
        x0h, Wt_out, b_out, out, N_NODES);
}